// Round 20
// baseline (874.361 us; speedup 1.0000x reference)
//
#include <hip/hip_runtime.h>
#include <hip/hip_bf16.h>

typedef unsigned short u16;
typedef short bf16x8 __attribute__((ext_vector_type(8)));
typedef unsigned short u16x8 __attribute__((ext_vector_type(8)));
typedef float f32x4 __attribute__((ext_vector_type(4)));

#define NB 4
#define NS 2048
#define DM 256
#define NH 4
#define DHD 64
#define MR (NB*NS)      /* 8192 */
#define BHC (NB*NH)     /* 16 */
#define NCHUNK 2
#define CKEYS (NS/NCHUNK)   /* 1024 */

__device__ __forceinline__ u16 f2b(float f){
    __hip_bfloat16 h = __float2bfloat16(f);
    return __builtin_bit_cast(u16, h);
}

#define MFMA16(a,b,c) __builtin_amdgcn_mfma_f32_16x16x32_bf16((a),(b),(c),0,0,0)

// ---------------- casts ----------------
__global__ void k_cast_bf16(const float* __restrict__ src, u16* __restrict__ dst, int n){
    int i = (blockIdx.x*blockDim.x + threadIdx.x)*4;
    if (i + 3 < n){
        float4 v = *(const float4*)(src + i);
        dst[i+0] = f2b(v.x); dst[i+1] = f2b(v.y); dst[i+2] = f2b(v.z); dst[i+3] = f2b(v.w);
    }
}
__global__ void k_cast_w_t(const float* __restrict__ W, u16* __restrict__ Wt, int K, int Nc){
    int idx = blockIdx.x*blockDim.x + threadIdx.x;
    if (idx >= K*Nc) return;
    int k = idx % K, nc = idx / K;
    Wt[idx] = f2b(W[(size_t)k*Nc + nc]);
}

// ---------------- MFMA GEMM: C[M,Nc] = A[M,K](bf16) * Wt[Nc,K]^T + bias(f32) ----------------
__global__ __launch_bounds__(256) void k_gemm(const u16* __restrict__ A, const u16* __restrict__ Wt,
                                              const float* __restrict__ bias, float* __restrict__ C,
                                              int K, int Nc){
    __shared__ __attribute__((aligned(16))) u16 As[64*72];
    __shared__ __attribute__((aligned(16))) u16 Bs[64*72];
    const int tid = threadIdx.x;
    const int lane = tid & 63, widx = tid >> 6;
    const int wr = widx >> 1, wc = widx & 1;
    const int r16 = lane & 15, g = lane >> 4;
    const int m0 = blockIdx.x * 64, n0 = blockIdx.y * 64;
    f32x4 acc[2][2] = {};
    const int nkt = K >> 6;
    for (int kt = 0; kt < nkt; ++kt){
#pragma unroll
        for (int it = 0; it < 2; ++it){
            int ch = tid + it*256;
            int row = ch >> 3, cc = ch & 7;
            u16x8 av = *(const u16x8*)(A  + (size_t)(m0+row)*K + kt*64 + cc*8);
            *(u16x8*)(As + row*72 + cc*8) = av;
            u16x8 bv = *(const u16x8*)(Wt + (size_t)(n0+row)*K + kt*64 + cc*8);
            *(u16x8*)(Bs + row*72 + cc*8) = bv;
        }
        __syncthreads();
#pragma unroll
        for (int s = 0; s < 2; ++s){
            bf16x8 a0 = *(const bf16x8*)(As + (wr*32 +      r16)*72 + s*32 + g*8);
            bf16x8 a1 = *(const bf16x8*)(As + (wr*32 + 16 + r16)*72 + s*32 + g*8);
            bf16x8 b0 = *(const bf16x8*)(Bs + (wc*32 +      r16)*72 + s*32 + g*8);
            bf16x8 b1 = *(const bf16x8*)(Bs + (wc*32 + 16 + r16)*72 + s*32 + g*8);
            acc[0][0] = MFMA16(a0, b0, acc[0][0]);
            acc[0][1] = MFMA16(a0, b1, acc[0][1]);
            acc[1][0] = MFMA16(a1, b0, acc[1][0]);
            acc[1][1] = MFMA16(a1, b1, acc[1][1]);
        }
        __syncthreads();
    }
#pragma unroll
    for (int mi = 0; mi < 2; ++mi)
#pragma unroll
    for (int ni = 0; ni < 2; ++ni){
        int row = m0 + wr*32 + mi*16 + g*4;
        int col = n0 + wc*32 + ni*16 + r16;
        float bc = bias[col];
        float* cp = C + (size_t)row*Nc + col;
#pragma unroll
        for (int rr = 0; rr < 4; ++rr) cp[(size_t)rr*Nc] = acc[mi][ni][rr] + bc;
    }
}

// ---------------- qkv epilogue ----------------
__global__ void k_qkv_epi(const float* __restrict__ C, const float* __restrict__ kp,
                          u16* __restrict__ Q, u16* __restrict__ K, u16* __restrict__ VT){
    int idx = blockIdx.x*blockDim.x + threadIdx.x;
    if (idx >= BHC*NS*32) return;
    int dhp = idx & 31;
    int n   = (idx >> 5) & (NS-1);
    int bh  = idx >> 16;
    int b = bh >> 2, h = bh & 3;
    size_t crow = (size_t)(b*NS + n)*768 + h*192 + dhp*6;
    float q0 = C[crow+0], k0 = C[crow+1], v0 = C[crow+2];
    float q1 = C[crow+3], k1 = C[crow+4], v1 = C[crow+5];
    size_t kb = (size_t)b*(NS*DHD) + (size_t)n*DHD + dhp*2;
    float c0 = kp[kb], c1 = kp[kb+1];
    float s0 = kp[kb + (size_t)NB*NS*DHD], s1 = kp[kb + (size_t)NB*NS*DHD + 1];
    float qr0 = q0*c0 - q1*s0, qr1 = q1*c1 + q0*s1;
    float kr0 = k0*c0 - k1*s0, kr1 = k1*c1 + k0*s1;
    size_t qk = ((size_t)bh*NS + n)*DHD + dhp*2;
    Q[qk]   = f2b(qr0); Q[qk+1] = f2b(qr1);
    K[qk]   = f2b(kr0); K[qk+1] = f2b(kr1);
    size_t vt = ((size_t)bh*DHD + dhp*2)*NS + n;
    VT[vt]      = f2b(v0);
    VT[vt + NS] = f2b(v1);
}

__global__ void k_qk_epi(const float* __restrict__ C, u16* __restrict__ Q){
    int idx = blockIdx.x*blockDim.x + threadIdx.x;
    if (idx >= BHC*NS*DHD) return;
    int dh = idx & 63; int n = (idx >> 6) & (NS-1); int bh = idx >> 17;
    int b = bh >> 2, h = bh & 3;
    Q[idx] = f2b(C[(size_t)(b*NS + n)*DM + h*DHD + dh]);
}
__global__ void k_v_epi(const float* __restrict__ C, u16* __restrict__ VT){
    int idx = blockIdx.x*blockDim.x + threadIdx.x;
    if (idx >= BHC*NS*DHD) return;
    int n = idx & (NS-1); int dh = (idx >> 11) & 63; int bh = idx >> 17;
    int b = bh >> 2, h = bh & 3;
    VT[idx] = f2b(C[(size_t)(b*NS + n)*DM + h*DHD + dh]);
}

// ---------------- MFMA flash attention v2: KV-split x2, j-tile 64 ----------------
// grid: (512, NCHUNK). wave = 16 q rows of one (bh, qb); partials (o,m,l) per chunk.
__global__ __launch_bounds__(256) void k_attn2(const u16* __restrict__ Q, const u16* __restrict__ Kb,
                                               const u16* __restrict__ VT,
                                               float* __restrict__ opart, float* __restrict__ mpart,
                                               float* __restrict__ lpart, float scale){
    __shared__ __attribute__((aligned(16))) u16 P_lds[4][16*68];
    const int tid = threadIdx.x, lane = tid & 63, widx = tid >> 6;
    const int r16 = lane & 15, g = lane >> 4;
    const int gw = blockIdx.x*4 + widx;
    const int bh = gw >> 7, qb = gw & 127;
    const int n0 = qb * 16;
    const int ck = blockIdx.y;
    const u16* Qp = Q + ((size_t)bh*NS + n0)*DHD;
    bf16x8 qf0 = *(const bf16x8*)(Qp + r16*DHD + g*8);
    bf16x8 qf1 = *(const bf16x8*)(Qp + r16*DHD + 32 + g*8);
    f32x4 o[4] = {};
    float m_[4], l_[4];
#pragma unroll
    for (int r = 0; r < 4; ++r){ m_[r] = -1e30f; l_[r] = 0.f; }
    u16* Pl = P_lds[widx];
    const u16* Vbase = VT + (size_t)bh*DHD*NS + ck*CKEYS;
    const u16* Kbase = Kb + ((size_t)bh*NS + ck*CKEYS)*DHD;

    for (int jt = 0; jt < CKEYS/64; ++jt){
        const u16* Kp = Kbase + (size_t)jt*64*DHD;
        f32x4 s[4] = {};
#pragma unroll
        for (int ks = 0; ks < 4; ++ks){
            bf16x8 k0 = *(const bf16x8*)(Kp + (ks*16+r16)*DHD + g*8);
            bf16x8 k1 = *(const bf16x8*)(Kp + (ks*16+r16)*DHD + 32 + g*8);
            s[ks] = MFMA16(qf0, k0, s[ks]);
            s[ks] = MFMA16(qf1, k1, s[ks]);
        }
#pragma unroll
        for (int r = 0; r < 4; ++r){
            float a0 = s[0][r]*scale, a1 = s[1][r]*scale, a2 = s[2][r]*scale, a3 = s[3][r]*scale;
            float rm = fmaxf(fmaxf(a0,a1), fmaxf(a2,a3));
            rm = fmaxf(rm, __shfl_xor(rm, 1));
            rm = fmaxf(rm, __shfl_xor(rm, 2));
            rm = fmaxf(rm, __shfl_xor(rm, 4));
            rm = fmaxf(rm, __shfl_xor(rm, 8));
            float mn = fmaxf(m_[r], rm);
            float corr = __expf(m_[r] - mn);
            float p0 = __expf(a0 - mn), p1 = __expf(a1 - mn);
            float p2 = __expf(a2 - mn), p3 = __expf(a3 - mn);
            float rs = (p0+p1) + (p2+p3);
            rs += __shfl_xor(rs, 1); rs += __shfl_xor(rs, 2);
            rs += __shfl_xor(rs, 4); rs += __shfl_xor(rs, 8);
            l_[r] = l_[r]*corr + rs;
            m_[r] = mn;
            o[0][r] *= corr; o[1][r] *= corr; o[2][r] *= corr; o[3][r] *= corr;
            int rowb = (g*4+r)*68;
            Pl[rowb +      r16] = f2b(p0);
            Pl[rowb + 16 + r16] = f2b(p1);
            Pl[rowb + 32 + r16] = f2b(p2);
            Pl[rowb + 48 + r16] = f2b(p3);
        }
        asm volatile("s_waitcnt lgkmcnt(0)" ::: "memory");
        __builtin_amdgcn_sched_barrier(0);
        bf16x8 pa0 = *(const bf16x8*)(Pl + r16*68 + g*8);
        bf16x8 pa1 = *(const bf16x8*)(Pl + r16*68 + 32 + g*8);
#pragma unroll
        for (int c = 0; c < 4; ++c){
            bf16x8 vb0 = *(const bf16x8*)(Vbase + (size_t)(c*16 + r16)*NS + jt*64 + g*8);
            bf16x8 vb1 = *(const bf16x8*)(Vbase + (size_t)(c*16 + r16)*NS + jt*64 + 32 + g*8);
            o[c] = MFMA16(pa0, vb0, o[c]);
            o[c] = MFMA16(pa1, vb1, o[c]);
        }
        __builtin_amdgcn_sched_barrier(0);
    }
    // store partials: opart[ck][bh][n][64] f32, m/l [ck][bh][n]
    const size_t rowbase = ((size_t)ck*BHC + bh)*NS + n0;
#pragma unroll
    for (int r = 0; r < 4; ++r){
        size_t row = rowbase + g*4 + r;
        if (r16 == 0){ mpart[row] = m_[r]; lpart[row] = l_[r]; }
        float* op = opart + row*64;
#pragma unroll
        for (int c = 0; c < 4; ++c) op[c*16 + r16] = o[c][r];
    }
}

// combine partials -> merged ctx bf16 (b,n,256)
__global__ __launch_bounds__(256) void k_attn_comb(const float* __restrict__ opart,
                                                   const float* __restrict__ mpart,
                                                   const float* __restrict__ lpart,
                                                   u16* __restrict__ ctx){
    int idx = blockIdx.x*256 + threadIdx.x;            // bh*NS*64
    if (idx >= BHC*NS*64) return;
    int d = idx & 63; int n = (idx >> 6) & (NS-1); int bh = idx >> 17;
    size_t row = (size_t)bh*NS + n;
    const size_t CH = (size_t)BHC*NS;
    float m0 = mpart[row], m1 = mpart[CH + row];
    float l0 = lpart[row], l1 = lpart[CH + row];
    float M = fmaxf(m0, m1);
    float e0 = __expf(m0 - M), e1 = __expf(m1 - M);
    float l = l0*e0 + l1*e1;
    float o0 = opart[row*64 + d], o1 = opart[(CH + row)*64 + d];
    float o = (o0*e0 + o1*e1) / l;
    int b = bh >> 2, h = bh & 3;
    ctx[((size_t)b*NS + n)*DM + h*DHD + d] = f2b(o);
}

// ---------------- FFN pieces ----------------
__global__ void k_msg_cat(const u16* __restrict__ Xb, const float* __restrict__ Cwo, u16* __restrict__ cat){
    int idx = blockIdx.x*blockDim.x + threadIdx.x;
    if (idx >= MR*DM) return;
    int c = idx & 255, row = idx >> 8;
    cat[(size_t)row*512 + c]       = Xb[idx];
    cat[(size_t)row*512 + 256 + c] = f2b(Cwo[idx]);
}

__global__ __launch_bounds__(256) void k_ln_gelu(const float* __restrict__ C, const float* __restrict__ gam,
                                                 const float* __restrict__ bet, u16* __restrict__ hb){
    int row = blockIdx.x, t = threadIdx.x;
    const float* cr = C + (size_t)row*512;
    float x0 = cr[t], x1 = cr[t+256];
    float s = x0 + x1, q = x0*x0 + x1*x1;
#pragma unroll
    for (int offs = 1; offs < 64; offs <<= 1){
        s += __shfl_xor(s, offs);
        q += __shfl_xor(q, offs);
    }
    __shared__ float ss[4], qq[4];
    int w = t >> 6, ln = t & 63;
    if (ln == 0){ ss[w] = s; qq[w] = q; }
    __syncthreads();
    s = ss[0]+ss[1]+ss[2]+ss[3];
    q = qq[0]+qq[1]+qq[2]+qq[3];
    float mu = s * (1.f/512.f);
    float var = q * (1.f/512.f) - mu*mu;
    float rs = rsqrtf(var + 1e-5f);
    float y0 = (x0 - mu)*rs*gam[t]     + bet[t];
    float y1 = (x1 - mu)*rs*gam[t+256] + bet[t+256];
    float g0 = 0.5f*y0*(1.f + erff(y0*0.70710678118654752f));
    float g1 = 0.5f*y1*(1.f + erff(y1*0.70710678118654752f));
    hb[(size_t)row*512 + t]       = f2b(g0);
    hb[(size_t)row*512 + 256 + t] = f2b(g1);
}

__global__ void k_resid_mid(const float* __restrict__ x, const float* __restrict__ C,
                            float* __restrict__ mid, u16* __restrict__ midb){
    int i = blockIdx.x*blockDim.x + threadIdx.x;
    if (i >= MR*DM) return;
    float v = x[i] + C[i];
    mid[i] = v; midb[i] = f2b(v);
}
__global__ void k_resid_out(const float* __restrict__ x, const float* __restrict__ C, float* __restrict__ outp){
    int i = blockIdx.x*blockDim.x + threadIdx.x;
    if (i >= MR*DM) return;
    outp[i] = x[i] + C[i];
}

// ---------------- host ----------------
extern "C" void kernel_launch(void* const* d_in, const int* in_sizes, int n_in,
                              void* d_out, int out_size, void* d_ws, size_t ws_size,
                              hipStream_t stream)
{
    const float* kp0   = (const float*)d_in[0];
    const float* kp1   = (const float*)d_in[1];
    const float* desc0 = (const float*)d_in[2];
    const float* desc1 = (const float*)d_in[3];
    const float* saWqkv= (const float*)d_in[4];
    const float* sabqkv= (const float*)d_in[5];
    const float* saWo  = (const float*)d_in[6];
    const float* sabo  = (const float*)d_in[7];
    const float* saW1  = (const float*)d_in[8];
    const float* sab1  = (const float*)d_in[9];
    const float* sag   = (const float*)d_in[10];
    const float* sabe  = (const float*)d_in[11];
    const float* saW2  = (const float*)d_in[12];
    const float* sab2  = (const float*)d_in[13];
    const float* caWqk = (const float*)d_in[14];
    const float* cabqk = (const float*)d_in[15];
    const float* caWv  = (const float*)d_in[16];
    const float* cabv  = (const float*)d_in[17];
    const float* caWo  = (const float*)d_in[18];
    const float* cabo  = (const float*)d_in[19];
    const float* caW1  = (const float*)d_in[20];
    const float* cab1  = (const float*)d_in[21];
    const float* cag   = (const float*)d_in[22];
    const float* cabe  = (const float*)d_in[23];
    const float* caW2  = (const float*)d_in[24];
    const float* cab2  = (const float*)d_in[25];

    char* ws = (char*)d_ws;
    size_t off = 0;
    auto alloc = [&](size_t b)->char*{ char* p = ws + off; off = (off + b + 255) & ~(size_t)255; return p; };

    u16* wqkvT = (u16*)alloc(768*256*2);
    u16* woST  = (u16*)alloc(256*256*2);
    u16* w1ST  = (u16*)alloc(512*512*2);
    u16* w2ST  = (u16*)alloc(256*512*2);
    u16* wqkT  = (u16*)alloc(256*256*2);
    u16* wvT   = (u16*)alloc(256*256*2);
    u16* woCT  = (u16*)alloc(256*256*2);
    u16* w1CT  = (u16*)alloc(512*512*2);
    u16* w2CT  = (u16*)alloc(256*512*2);
    u16* X0b   = (u16*)alloc((size_t)MR*DM*2);
    u16* X1b   = (u16*)alloc((size_t)MR*DM*2);
    u16* Qb    = (u16*)alloc((size_t)MR*DM*2);
    u16* Kbf   = (u16*)alloc((size_t)MR*DM*2);
    u16* VTa   = (u16*)alloc((size_t)MR*DM*2);
    u16* VT0   = (u16*)alloc((size_t)MR*DM*2);
    u16* ctxb  = (u16*)alloc((size_t)MR*DM*2);
    u16* midb0 = (u16*)alloc((size_t)MR*DM*2);
    u16* midb1 = (u16*)alloc((size_t)MR*DM*2);
    u16* catb  = (u16*)alloc((size_t)MR*512*2);
    u16* hb    = (u16*)alloc((size_t)MR*512*2);
    float* Cbuf= (float*)alloc((size_t)MR*768*4);
    float* mid0= (float*)alloc((size_t)MR*DM*4);
    float* mid1= (float*)alloc((size_t)MR*DM*4);
    float* opart = (float*)alloc((size_t)NCHUNK*BHC*NS*64*4);
    float* mpart = (float*)alloc((size_t)NCHUNK*BHC*NS*4);
    float* lpart = (float*)alloc((size_t)NCHUNK*BHC*NS*4);

    k_cast_w_t<<<768, 256, 0, stream>>>(saWqkv, wqkvT, 256, 768);
    k_cast_w_t<<<256, 256, 0, stream>>>(saWo,  woST, 256, 256);
    k_cast_w_t<<<1024,256, 0, stream>>>(saW1,  w1ST, 512, 512);
    k_cast_w_t<<<512, 256, 0, stream>>>(saW2,  w2ST, 512, 256);
    k_cast_w_t<<<256, 256, 0, stream>>>(caWqk, wqkT, 256, 256);
    k_cast_w_t<<<256, 256, 0, stream>>>(caWv,  wvT,  256, 256);
    k_cast_w_t<<<256, 256, 0, stream>>>(caWo,  woCT, 256, 256);
    k_cast_w_t<<<1024,256, 0, stream>>>(caW1,  w1CT, 512, 512);
    k_cast_w_t<<<512, 256, 0, stream>>>(caW2,  w2CT, 512, 256);
    k_cast_bf16<<<2048, 256, 0, stream>>>(desc0, X0b, MR*DM);
    k_cast_bf16<<<2048, 256, 0, stream>>>(desc1, X1b, MR*DM);

    const dim3 AG(512, NCHUNK);

    // ---- self block 0 ----
    k_gemm<<<dim3(128,12),256,0,stream>>>(X0b, wqkvT, sabqkv, Cbuf, 256, 768);
    k_qkv_epi<<<4096,256,0,stream>>>(Cbuf, kp0, Qb, Kbf, VTa);
    k_attn2<<<AG,256,0,stream>>>(Qb, Kbf, VTa, opart, mpart, lpart, 0.125f);
    k_attn_comb<<<8192,256,0,stream>>>(opart, mpart, lpart, ctxb);
    k_gemm<<<dim3(128,4),256,0,stream>>>(ctxb, woST, sabo, Cbuf, 256, 256);
    k_msg_cat<<<8192,256,0,stream>>>(X0b, Cbuf, catb);
    k_gemm<<<dim3(128,8),256,0,stream>>>(catb, w1ST, sab1, Cbuf, 512, 512);
    k_ln_gelu<<<8192,256,0,stream>>>(Cbuf, sag, sabe, hb);
    k_gemm<<<dim3(128,4),256,0,stream>>>(hb, w2ST, sab2, Cbuf, 512, 256);
    k_resid_mid<<<8192,256,0,stream>>>(desc0, Cbuf, mid0, midb0);

    // ---- self block 1 ----
    k_gemm<<<dim3(128,12),256,0,stream>>>(X1b, wqkvT, sabqkv, Cbuf, 256, 768);
    k_qkv_epi<<<4096,256,0,stream>>>(Cbuf, kp1, Qb, Kbf, VTa);
    k_attn2<<<AG,256,0,stream>>>(Qb, Kbf, VTa, opart, mpart, lpart, 0.125f);
    k_attn_comb<<<8192,256,0,stream>>>(opart, mpart, lpart, ctxb);
    k_gemm<<<dim3(128,4),256,0,stream>>>(ctxb, woST, sabo, Cbuf, 256, 256);
    k_msg_cat<<<8192,256,0,stream>>>(X1b, Cbuf, catb);
    k_gemm<<<dim3(128,8),256,0,stream>>>(catb, w1ST, sab1, Cbuf, 512, 512);
    k_ln_gelu<<<8192,256,0,stream>>>(Cbuf, sag, sabe, hb);
    k_gemm<<<dim3(128,4),256,0,stream>>>(hb, w2ST, sab2, Cbuf, 512, 256);
    k_resid_mid<<<8192,256,0,stream>>>(desc1, Cbuf, mid1, midb1);

    // ---- cross projections ----
    k_gemm<<<dim3(128,4),256,0,stream>>>(midb0, wqkT, cabqk, Cbuf, 256, 256);
    k_qk_epi<<<8192,256,0,stream>>>(Cbuf, Qb);                      // qk0
    k_gemm<<<dim3(128,4),256,0,stream>>>(midb1, wqkT, cabqk, Cbuf, 256, 256);
    k_qk_epi<<<8192,256,0,stream>>>(Cbuf, Kbf);                     // qk1
    k_gemm<<<dim3(128,4),256,0,stream>>>(midb1, wvT, cabv, Cbuf, 256, 256);
    k_v_epi<<<8192,256,0,stream>>>(Cbuf, VTa);                      // v1^T
    k_gemm<<<dim3(128,4),256,0,stream>>>(midb0, wvT, cabv, Cbuf, 256, 256);
    k_v_epi<<<8192,256,0,stream>>>(Cbuf, VT0);                      // v0^T

    float* out0 = (float*)d_out;
    float* out1 = out0 + (size_t)MR*DM;

    // ---- cross side 0: sdpa(qk0, qk1, v1) + FFN ----
    k_attn2<<<AG,256,0,stream>>>(Qb, Kbf, VTa, opart, mpart, lpart, 0.125f);
    k_attn_comb<<<8192,256,0,stream>>>(opart, mpart, lpart, ctxb);
    k_gemm<<<dim3(128,4),256,0,stream>>>(ctxb, woCT, cabo, Cbuf, 256, 256);
    k_msg_cat<<<8192,256,0,stream>>>(midb0, Cbuf, catb);
    k_gemm<<<dim3(128,8),256,0,stream>>>(catb, w1CT, cab1, Cbuf, 512, 512);
    k_ln_gelu<<<8192,256,0,stream>>>(Cbuf, cag, cabe, hb);
    k_gemm<<<dim3(128,4),256,0,stream>>>(hb, w2CT, cab2, Cbuf, 512, 256);
    k_resid_out<<<8192,256,0,stream>>>(mid0, Cbuf, out0);

    // ---- cross side 1: sdpa(qk1, qk0, v0) + FFN ----
    k_attn2<<<AG,256,0,stream>>>(Kbf, Qb, VT0, opart, mpart, lpart, 0.125f);
    k_attn_comb<<<8192,256,0,stream>>>(opart, mpart, lpart, ctxb);
    k_gemm<<<dim3(128,4),256,0,stream>>>(ctxb, woCT, cabo, Cbuf, 256, 256);
    k_msg_cat<<<8192,256,0,stream>>>(midb1, Cbuf, catb);
    k_gemm<<<dim3(128,8),256,0,stream>>>(catb, w1CT, cab1, Cbuf, 512, 512);
    k_ln_gelu<<<8192,256,0,stream>>>(Cbuf, cag, cabe, hb);
    k_gemm<<<dim3(128,4),256,0,stream>>>(hb, w2CT, cab2, Cbuf, 512, 256);
    k_resid_out<<<8192,256,0,stream>>>(mid1, Cbuf, out1);

    (void)in_sizes; (void)n_in; (void)out_size; (void)ws_size;
}

// Round 21
// 669.449 us; speedup vs baseline: 1.3061x; 1.3061x over previous
//
#include <hip/hip_runtime.h>
#include <hip/hip_bf16.h>

typedef unsigned short u16;
typedef short bf16x8 __attribute__((ext_vector_type(8)));
typedef unsigned short u16x8 __attribute__((ext_vector_type(8)));
typedef float f32x4 __attribute__((ext_vector_type(4)));
typedef float f32x16 __attribute__((ext_vector_type(16)));

#define NB 4
#define NS 2048
#define DM 256
#define NH 4
#define DHD 64
#define MR (NB*NS)      /* 8192 */
#define BHC (NB*NH)     /* 16 */
#define ACH 4
#define ACK (NS/ACH)    /* 512 keys per chunk */

__device__ __forceinline__ u16 f2b(float f){
    __hip_bfloat16 h = __float2bfloat16(f);
    return __builtin_bit_cast(u16, h);
}
__device__ __forceinline__ float b2f(u16 u){
    unsigned v = ((unsigned)u) << 16; float f; __builtin_memcpy(&f, &v, 4); return f;
}

#define MFMA16(a,b,c) __builtin_amdgcn_mfma_f32_16x16x32_bf16((a),(b),(c),0,0,0)
#define MFMA32(a,b,c) __builtin_amdgcn_mfma_f32_32x32x16_bf16((a),(b),(c),0,0,0)

// ---------------- casts ----------------
__global__ void k_cast_bf16(const float* __restrict__ src, u16* __restrict__ dst, int n){
    int i = (blockIdx.x*blockDim.x + threadIdx.x)*4;
    if (i + 3 < n){
        float4 v = *(const float4*)(src + i);
        dst[i+0] = f2b(v.x); dst[i+1] = f2b(v.y); dst[i+2] = f2b(v.z); dst[i+3] = f2b(v.w);
    }
}
__global__ void k_cast_w_t(const float* __restrict__ W, u16* __restrict__ Wt, int K, int Nc){
    int idx = blockIdx.x*blockDim.x + threadIdx.x;
    if (idx >= K*Nc) return;
    int k = idx % K, nc = idx / K;
    Wt[idx] = f2b(W[(size_t)k*Nc + nc]);
}

// ---------------- MFMA GEMM (unchanged) ----------------
__global__ __launch_bounds__(256) void k_gemm(const u16* __restrict__ A, const u16* __restrict__ Wt,
                                              const float* __restrict__ bias, float* __restrict__ C,
                                              int K, int Nc){
    __shared__ __attribute__((aligned(16))) u16 As[64*72];
    __shared__ __attribute__((aligned(16))) u16 Bs[64*72];
    const int tid = threadIdx.x;
    const int lane = tid & 63, widx = tid >> 6;
    const int wr = widx >> 1, wc = widx & 1;
    const int r16 = lane & 15, g = lane >> 4;
    const int m0 = blockIdx.x * 64, n0 = blockIdx.y * 64;
    f32x4 acc[2][2] = {};
    const int nkt = K >> 6;
    for (int kt = 0; kt < nkt; ++kt){
#pragma unroll
        for (int it = 0; it < 2; ++it){
            int ch = tid + it*256;
            int row = ch >> 3, cc = ch & 7;
            u16x8 av = *(const u16x8*)(A  + (size_t)(m0+row)*K + kt*64 + cc*8);
            *(u16x8*)(As + row*72 + cc*8) = av;
            u16x8 bv = *(const u16x8*)(Wt + (size_t)(n0+row)*K + kt*64 + cc*8);
            *(u16x8*)(Bs + row*72 + cc*8) = bv;
        }
        __syncthreads();
#pragma unroll
        for (int s = 0; s < 2; ++s){
            bf16x8 a0 = *(const bf16x8*)(As + (wr*32 +      r16)*72 + s*32 + g*8);
            bf16x8 a1 = *(const bf16x8*)(As + (wr*32 + 16 + r16)*72 + s*32 + g*8);
            bf16x8 b0 = *(const bf16x8*)(Bs + (wc*32 +      r16)*72 + s*32 + g*8);
            bf16x8 b1 = *(const bf16x8*)(Bs + (wc*32 + 16 + r16)*72 + s*32 + g*8);
            acc[0][0] = MFMA16(a0, b0, acc[0][0]);
            acc[0][1] = MFMA16(a0, b1, acc[0][1]);
            acc[1][0] = MFMA16(a1, b0, acc[1][0]);
            acc[1][1] = MFMA16(a1, b1, acc[1][1]);
        }
        __syncthreads();
    }
#pragma unroll
    for (int mi = 0; mi < 2; ++mi)
#pragma unroll
    for (int ni = 0; ni < 2; ++ni){
        int row = m0 + wr*32 + mi*16 + g*4;
        int col = n0 + wc*32 + ni*16 + r16;
        float bc = bias[col];
        float* cp = C + (size_t)row*Nc + col;
#pragma unroll
        for (int rr = 0; rr < 4; ++rr) cp[(size_t)rr*Nc] = acc[mi][ni][rr] + bc;
    }
}

// ---------------- qkv epilogue ----------------
__global__ void k_qkv_epi(const float* __restrict__ C, const float* __restrict__ kp,
                          u16* __restrict__ Q, u16* __restrict__ K, u16* __restrict__ VT){
    int idx = blockIdx.x*blockDim.x + threadIdx.x;
    if (idx >= BHC*NS*32) return;
    int dhp = idx & 31;
    int n   = (idx >> 5) & (NS-1);
    int bh  = idx >> 16;
    int b = bh >> 2, h = bh & 3;
    size_t crow = (size_t)(b*NS + n)*768 + h*192 + dhp*6;
    float q0 = C[crow+0], k0 = C[crow+1], v0 = C[crow+2];
    float q1 = C[crow+3], k1 = C[crow+4], v1 = C[crow+5];
    size_t kb = (size_t)b*(NS*DHD) + (size_t)n*DHD + dhp*2;
    float c0 = kp[kb], c1 = kp[kb+1];
    float s0 = kp[kb + (size_t)NB*NS*DHD], s1 = kp[kb + (size_t)NB*NS*DHD + 1];
    float qr0 = q0*c0 - q1*s0, qr1 = q1*c1 + q0*s1;
    float kr0 = k0*c0 - k1*s0, kr1 = k1*c1 + k0*s1;
    size_t qk = ((size_t)bh*NS + n)*DHD + dhp*2;
    Q[qk]   = f2b(qr0); Q[qk+1] = f2b(qr1);
    K[qk]   = f2b(kr0); K[qk+1] = f2b(kr1);
    size_t vt = ((size_t)bh*DHD + dhp*2)*NS + n;
    VT[vt]      = f2b(v0);
    VT[vt + NS] = f2b(v1);
}

__global__ void k_qk_epi(const float* __restrict__ C, u16* __restrict__ Q){
    int idx = blockIdx.x*blockDim.x + threadIdx.x;
    if (idx >= BHC*NS*DHD) return;
    int dh = idx & 63; int n = (idx >> 6) & (NS-1); int bh = idx >> 17;
    int b = bh >> 2, h = bh & 3;
    Q[idx] = f2b(C[(size_t)(b*NS + n)*DM + h*DHD + dh]);
}
__global__ void k_v_epi(const float* __restrict__ C, u16* __restrict__ VT){
    int idx = blockIdx.x*blockDim.x + threadIdx.x;
    if (idx >= BHC*NS*DHD) return;
    int n = idx & (NS-1); int dh = (idx >> 11) & 63; int bh = idx >> 17;
    int b = bh >> 2, h = bh & 3;
    VT[idx] = f2b(C[(size_t)(b*NS + n)*DM + h*DHD + dh]);
}

// ---------------- attention v3: swapped-operand 32x32 MFMA, lane-local softmax, no LDS ----------------
// wave = 32 queries; grid (256, ACH). partials: o (bf16), m,l (f32).
__global__ __launch_bounds__(256) void k_attn3(const u16* __restrict__ Q, const u16* __restrict__ Kb,
                                               const u16* __restrict__ VT,
                                               u16* __restrict__ opart, float* __restrict__ mpart,
                                               float* __restrict__ lpart, float scale){
    const int tid = threadIdx.x, lane = tid & 63, widx = tid >> 6;
    const int l31 = lane & 31, hi = lane >> 5;
    const int gw = blockIdx.x*4 + widx;       // 0..1023
    const int bh = gw >> 6, qt = gw & 63;
    const int q0 = qt * 32;
    const int ck = blockIdx.y;

    // Q B-frag (col=query=l31, k=8*hi+i), pre-scaled by `scale` (exact pow2)
    bf16x8 qf[4];
    {
        const u16* Qp = Q + ((size_t)bh*NS + q0 + l31)*DHD + hi*8;
#pragma unroll
        for (int kk = 0; kk < 4; ++kk){
            u16x8 raw = *(const u16x8*)(Qp + kk*16);
            u16x8 sc;
#pragma unroll
            for (int i = 0; i < 8; ++i) sc[i] = f2b(b2f(raw[i]) * scale);
            qf[kk] = __builtin_bit_cast(bf16x8, sc);
        }
    }

    f32x16 o0 = {}, o1 = {};
    float m_run = -1e30f, l_run = 0.f;
    const u16* Kbase = Kb + ((size_t)bh*NS + ck*ACK)*DHD;
    const u16* Vb0 = VT + ((size_t)bh*DHD +      l31)*NS + ck*ACK;
    const u16* Vb1 = VT + ((size_t)bh*DHD + 32 + l31)*NS + ck*ACK;

    for (int jt = 0; jt < ACK/32; ++jt){
        // QK^T swapped: S^T[key, query]
        const u16* Kp = Kbase + (size_t)(jt*32 + l31)*DHD + hi*8;
        f32x16 s = {};
#pragma unroll
        for (int kk = 0; kk < 4; ++kk){
            bf16x8 kf = *(const bf16x8*)(Kp + kk*16);
            s = MFMA32(kf, qf[kk], s);
        }
        // lane-local softmax (lane = query; 16 keys here, 16 in lane^32)
        float mx = s[0];
#pragma unroll
        for (int i = 1; i < 16; ++i) mx = fmaxf(mx, s[i]);
        mx = fmaxf(mx, __shfl_xor(mx, 32));
        float mn = fmaxf(m_run, mx);
        float corr = __expf(m_run - mn);
        float p[16]; float sum = 0.f;
#pragma unroll
        for (int i = 0; i < 16; ++i){ p[i] = __expf(s[i] - mn); sum += p[i]; }
        sum += __shfl_xor(sum, 32);
        l_run = l_run*corr + sum;
        m_run = mn;
        o0 *= corr; o1 *= corr;
        // pack P into B-frags (col=query, k=key)
        unsigned c[8], x[8];
#pragma unroll
        for (int i = 0; i < 8; ++i){
            c[i] = ((unsigned)f2b(p[2*i+1]) << 16) | (unsigned)f2b(p[2*i]);
        }
#pragma unroll
        for (int i = 0; i < 8; ++i) x[i] = __shfl_xor(c[i], 32);
        unsigned pb0w[4], pb1w[4];
        pb0w[0] = hi ? x[2] : c[0];  pb0w[1] = hi ? x[3] : c[1];
        pb0w[2] = hi ? c[2] : x[0];  pb0w[3] = hi ? c[3] : x[1];
        pb1w[0] = hi ? x[6] : c[4];  pb1w[1] = hi ? x[7] : c[5];
        pb1w[2] = hi ? c[6] : x[4];  pb1w[3] = hi ? c[7] : x[5];
        bf16x8 pb0, pb1;
        __builtin_memcpy(&pb0, pb0w, 16);
        __builtin_memcpy(&pb1, pb1w, 16);
        // PV swapped: out^T[d, query] = V^T[d,k] x P[k,query]
        bf16x8 v00 = *(const bf16x8*)(Vb0 + jt*32 +      hi*8);
        bf16x8 v01 = *(const bf16x8*)(Vb0 + jt*32 + 16 + hi*8);
        bf16x8 v10 = *(const bf16x8*)(Vb1 + jt*32 +      hi*8);
        bf16x8 v11 = *(const bf16x8*)(Vb1 + jt*32 + 16 + hi*8);
        o0 = MFMA32(v00, pb0, o0);
        o0 = MFMA32(v01, pb1, o0);
        o1 = MFMA32(v10, pb0, o1);
        o1 = MFMA32(v11, pb1, o1);
    }
    // store partials: lane = query q0+l31
    const size_t rowb = ((size_t)ck*BHC + bh)*NS + q0;
    const size_t rq = rowb + l31;
    if (!hi){ mpart[rq] = m_run; lpart[rq] = l_run; }
    u16* op = opart + rq*64;
#pragma unroll
    for (int r = 0; r < 16; ++r){
        int d = (r & 3) + 8*(r >> 2) + 4*hi;
        op[d]      = f2b(o0[r]);
        op[d + 32] = f2b(o1[r]);
    }
}

// combine 4 chunks -> ctx bf16 (b,n,256)
__global__ __launch_bounds__(256) void k_attn_comb(const u16* __restrict__ opart,
                                                   const float* __restrict__ mpart,
                                                   const float* __restrict__ lpart,
                                                   u16* __restrict__ ctx){
    int idx = blockIdx.x*256 + threadIdx.x;            // bh*NS*64
    if (idx >= BHC*NS*64) return;
    int d = idx & 63; int n = (idx >> 6) & (NS-1); int bh = idx >> 17;
    size_t row = (size_t)bh*NS + n;
    const size_t CH = (size_t)BHC*NS;
    float M = -1e30f;
#pragma unroll
    for (int ck = 0; ck < ACH; ++ck) M = fmaxf(M, mpart[ck*CH + row]);
    float l = 0.f, o = 0.f;
#pragma unroll
    for (int ck = 0; ck < ACH; ++ck){
        float e = __expf(mpart[ck*CH + row] - M);
        l += lpart[ck*CH + row] * e;
        o += b2f(opart[(ck*CH + row)*64 + d]) * e;
    }
    int b = bh >> 2, h = bh & 3;
    ctx[((size_t)b*NS + n)*DM + h*DHD + d] = f2b(o / l);
}

// ---------------- FFN pieces ----------------
__global__ void k_msg_cat(const u16* __restrict__ Xb, const float* __restrict__ Cwo, u16* __restrict__ cat){
    int idx = blockIdx.x*blockDim.x + threadIdx.x;
    if (idx >= MR*DM) return;
    int c = idx & 255, row = idx >> 8;
    cat[(size_t)row*512 + c]       = Xb[idx];
    cat[(size_t)row*512 + 256 + c] = f2b(Cwo[idx]);
}

__global__ __launch_bounds__(256) void k_ln_gelu(const float* __restrict__ C, const float* __restrict__ gam,
                                                 const float* __restrict__ bet, u16* __restrict__ hb){
    int row = blockIdx.x, t = threadIdx.x;
    const float* cr = C + (size_t)row*512;
    float x0 = cr[t], x1 = cr[t+256];
    float s = x0 + x1, q = x0*x0 + x1*x1;
#pragma unroll
    for (int offs = 1; offs < 64; offs <<= 1){
        s += __shfl_xor(s, offs);
        q += __shfl_xor(q, offs);
    }
    __shared__ float ss[4], qq[4];
    int w = t >> 6, ln = t & 63;
    if (ln == 0){ ss[w] = s; qq[w] = q; }
    __syncthreads();
    s = ss[0]+ss[1]+ss[2]+ss[3];
    q = qq[0]+qq[1]+qq[2]+qq[3];
    float mu = s * (1.f/512.f);
    float var = q * (1.f/512.f) - mu*mu;
    float rs = rsqrtf(var + 1e-5f);
    float y0 = (x0 - mu)*rs*gam[t]     + bet[t];
    float y1 = (x1 - mu)*rs*gam[t+256] + bet[t+256];
    float g0 = 0.5f*y0*(1.f + erff(y0*0.70710678118654752f));
    float g1 = 0.5f*y1*(1.f + erff(y1*0.70710678118654752f));
    hb[(size_t)row*512 + t]       = f2b(g0);
    hb[(size_t)row*512 + 256 + t] = f2b(g1);
}

__global__ void k_resid_mid(const float* __restrict__ x, const float* __restrict__ C,
                            float* __restrict__ mid, u16* __restrict__ midb){
    int i = blockIdx.x*blockDim.x + threadIdx.x;
    if (i >= MR*DM) return;
    float v = x[i] + C[i];
    mid[i] = v; midb[i] = f2b(v);
}
__global__ void k_resid_out(const float* __restrict__ x, const float* __restrict__ C, float* __restrict__ outp){
    int i = blockIdx.x*blockDim.x + threadIdx.x;
    if (i >= MR*DM) return;
    outp[i] = x[i] + C[i];
}

// ---------------- host ----------------
extern "C" void kernel_launch(void* const* d_in, const int* in_sizes, int n_in,
                              void* d_out, int out_size, void* d_ws, size_t ws_size,
                              hipStream_t stream)
{
    const float* kp0   = (const float*)d_in[0];
    const float* kp1   = (const float*)d_in[1];
    const float* desc0 = (const float*)d_in[2];
    const float* desc1 = (const float*)d_in[3];
    const float* saWqkv= (const float*)d_in[4];
    const float* sabqkv= (const float*)d_in[5];
    const float* saWo  = (const float*)d_in[6];
    const float* sabo  = (const float*)d_in[7];
    const float* saW1  = (const float*)d_in[8];
    const float* sab1  = (const float*)d_in[9];
    const float* sag   = (const float*)d_in[10];
    const float* sabe  = (const float*)d_in[11];
    const float* saW2  = (const float*)d_in[12];
    const float* sab2  = (const float*)d_in[13];
    const float* caWqk = (const float*)d_in[14];
    const float* cabqk = (const float*)d_in[15];
    const float* caWv  = (const float*)d_in[16];
    const float* cabv  = (const float*)d_in[17];
    const float* caWo  = (const float*)d_in[18];
    const float* cabo  = (const float*)d_in[19];
    const float* caW1  = (const float*)d_in[20];
    const float* cab1  = (const float*)d_in[21];
    const float* cag   = (const float*)d_in[22];
    const float* cabe  = (const float*)d_in[23];
    const float* caW2  = (const float*)d_in[24];
    const float* cab2  = (const float*)d_in[25];

    char* ws = (char*)d_ws;
    size_t off = 0;
    auto alloc = [&](size_t b)->char*{ char* p = ws + off; off = (off + b + 255) & ~(size_t)255; return p; };

    u16* wqkvT = (u16*)alloc(768*256*2);
    u16* woST  = (u16*)alloc(256*256*2);
    u16* w1ST  = (u16*)alloc(512*512*2);
    u16* w2ST  = (u16*)alloc(256*512*2);
    u16* wqkT  = (u16*)alloc(256*256*2);
    u16* wvT   = (u16*)alloc(256*256*2);
    u16* woCT  = (u16*)alloc(256*256*2);
    u16* w1CT  = (u16*)alloc(512*512*2);
    u16* w2CT  = (u16*)alloc(256*512*2);
    u16* X0b   = (u16*)alloc((size_t)MR*DM*2);
    u16* X1b   = (u16*)alloc((size_t)MR*DM*2);
    u16* Qb    = (u16*)alloc((size_t)MR*DM*2);
    u16* Kbf   = (u16*)alloc((size_t)MR*DM*2);
    u16* VTa   = (u16*)alloc((size_t)MR*DM*2);
    u16* VT0   = (u16*)alloc((size_t)MR*DM*2);
    u16* ctxb  = (u16*)alloc((size_t)MR*DM*2);
    u16* midb0 = (u16*)alloc((size_t)MR*DM*2);
    u16* midb1 = (u16*)alloc((size_t)MR*DM*2);
    u16* catb  = (u16*)alloc((size_t)MR*512*2);
    u16* hb    = (u16*)alloc((size_t)MR*512*2);
    float* Cbuf= (float*)alloc((size_t)MR*768*4);
    float* mid0= (float*)alloc((size_t)MR*DM*4);
    float* mid1= (float*)alloc((size_t)MR*DM*4);
    u16*  opart = (u16*)alloc((size_t)ACH*BHC*NS*64*2);
    float* mpart = (float*)alloc((size_t)ACH*BHC*NS*4);
    float* lpart = (float*)alloc((size_t)ACH*BHC*NS*4);

    k_cast_w_t<<<768, 256, 0, stream>>>(saWqkv, wqkvT, 256, 768);
    k_cast_w_t<<<256, 256, 0, stream>>>(saWo,  woST, 256, 256);
    k_cast_w_t<<<1024,256, 0, stream>>>(saW1,  w1ST, 512, 512);
    k_cast_w_t<<<512, 256, 0, stream>>>(saW2,  w2ST, 512, 256);
    k_cast_w_t<<<256, 256, 0, stream>>>(caWqk, wqkT, 256, 256);
    k_cast_w_t<<<256, 256, 0, stream>>>(caWv,  wvT,  256, 256);
    k_cast_w_t<<<256, 256, 0, stream>>>(caWo,  woCT, 256, 256);
    k_cast_w_t<<<1024,256, 0, stream>>>(caW1,  w1CT, 512, 512);
    k_cast_w_t<<<512, 256, 0, stream>>>(caW2,  w2CT, 512, 256);
    k_cast_bf16<<<2048, 256, 0, stream>>>(desc0, X0b, MR*DM);
    k_cast_bf16<<<2048, 256, 0, stream>>>(desc1, X1b, MR*DM);

    const dim3 AG(256, ACH);

    // ---- self block 0 ----
    k_gemm<<<dim3(128,12),256,0,stream>>>(X0b, wqkvT, sabqkv, Cbuf, 256, 768);
    k_qkv_epi<<<4096,256,0,stream>>>(Cbuf, kp0, Qb, Kbf, VTa);
    k_attn3<<<AG,256,0,stream>>>(Qb, Kbf, VTa, opart, mpart, lpart, 0.125f);
    k_attn_comb<<<8192,256,0,stream>>>(opart, mpart, lpart, ctxb);
    k_gemm<<<dim3(128,4),256,0,stream>>>(ctxb, woST, sabo, Cbuf, 256, 256);
    k_msg_cat<<<8192,256,0,stream>>>(X0b, Cbuf, catb);
    k_gemm<<<dim3(128,8),256,0,stream>>>(catb, w1ST, sab1, Cbuf, 512, 512);
    k_ln_gelu<<<8192,256,0,stream>>>(Cbuf, sag, sabe, hb);
    k_gemm<<<dim3(128,4),256,0,stream>>>(hb, w2ST, sab2, Cbuf, 512, 256);
    k_resid_mid<<<8192,256,0,stream>>>(desc0, Cbuf, mid0, midb0);

    // ---- self block 1 ----
    k_gemm<<<dim3(128,12),256,0,stream>>>(X1b, wqkvT, sabqkv, Cbuf, 256, 768);
    k_qkv_epi<<<4096,256,0,stream>>>(Cbuf, kp1, Qb, Kbf, VTa);
    k_attn3<<<AG,256,0,stream>>>(Qb, Kbf, VTa, opart, mpart, lpart, 0.125f);
    k_attn_comb<<<8192,256,0,stream>>>(opart, mpart, lpart, ctxb);
    k_gemm<<<dim3(128,4),256,0,stream>>>(ctxb, woST, sabo, Cbuf, 256, 256);
    k_msg_cat<<<8192,256,0,stream>>>(X1b, Cbuf, catb);
    k_gemm<<<dim3(128,8),256,0,stream>>>(catb, w1ST, sab1, Cbuf, 512, 512);
    k_ln_gelu<<<8192,256,0,stream>>>(Cbuf, sag, sabe, hb);
    k_gemm<<<dim3(128,4),256,0,stream>>>(hb, w2ST, sab2, Cbuf, 512, 256);
    k_resid_mid<<<8192,256,0,stream>>>(desc1, Cbuf, mid1, midb1);

    // ---- cross projections ----
    k_gemm<<<dim3(128,4),256,0,stream>>>(midb0, wqkT, cabqk, Cbuf, 256, 256);
    k_qk_epi<<<8192,256,0,stream>>>(Cbuf, Qb);                      // qk0
    k_gemm<<<dim3(128,4),256,0,stream>>>(midb1, wqkT, cabqk, Cbuf, 256, 256);
    k_qk_epi<<<8192,256,0,stream>>>(Cbuf, Kbf);                     // qk1
    k_gemm<<<dim3(128,4),256,0,stream>>>(midb1, wvT, cabv, Cbuf, 256, 256);
    k_v_epi<<<8192,256,0,stream>>>(Cbuf, VTa);                      // v1^T
    k_gemm<<<dim3(128,4),256,0,stream>>>(midb0, wvT, cabv, Cbuf, 256, 256);
    k_v_epi<<<8192,256,0,stream>>>(Cbuf, VT0);                      // v0^T

    float* out0 = (float*)d_out;
    float* out1 = out0 + (size_t)MR*DM;

    // ---- cross side 0 ----
    k_attn3<<<AG,256,0,stream>>>(Qb, Kbf, VTa, opart, mpart, lpart, 0.125f);
    k_attn_comb<<<8192,256,0,stream>>>(opart, mpart, lpart, ctxb);
    k_gemm<<<dim3(128,4),256,0,stream>>>(ctxb, woCT, cabo, Cbuf, 256, 256);
    k_msg_cat<<<8192,256,0,stream>>>(midb0, Cbuf, catb);
    k_gemm<<<dim3(128,8),256,0,stream>>>(catb, w1CT, cab1, Cbuf, 512, 512);
    k_ln_gelu<<<8192,256,0,stream>>>(Cbuf, cag, cabe, hb);
    k_gemm<<<dim3(128,4),256,0,stream>>>(hb, w2CT, cab2, Cbuf, 512, 256);
    k_resid_out<<<8192,256,0,stream>>>(mid0, Cbuf, out0);

    // ---- cross side 1 ----
    k_attn3<<<AG,256,0,stream>>>(Kbf, Qb, VT0, opart, mpart, lpart, 0.125f);
    k_attn_comb<<<8192,256,0,stream>>>(opart, mpart, lpart, ctxb);
    k_gemm<<<dim3(128,4),256,0,stream>>>(ctxb, woCT, cabo, Cbuf, 256, 256);
    k_msg_cat<<<8192,256,0,stream>>>(midb1, Cbuf, catb);
    k_gemm<<<dim3(128,8),256,0,stream>>>(catb, w1CT, cab1, Cbuf, 512, 512);
    k_ln_gelu<<<8192,256,0,stream>>>(Cbuf, cag, cabe, hb);
    k_gemm<<<dim3(128,4),256,0,stream>>>(hb, w2CT, cab2, Cbuf, 512, 256);
    k_resid_out<<<8192,256,0,stream>>>(mid1, Cbuf, out1);

    (void)in_sizes; (void)n_in; (void)out_size; (void)ws_size;
}

// Round 22
// 621.830 us; speedup vs baseline: 1.4061x; 1.0766x over previous
//
#include <hip/hip_runtime.h>
#include <hip/hip_bf16.h>

typedef unsigned short u16;
typedef short bf16x8 __attribute__((ext_vector_type(8)));
typedef unsigned short u16x8 __attribute__((ext_vector_type(8)));
typedef float f32x4 __attribute__((ext_vector_type(4)));
typedef float f32x16 __attribute__((ext_vector_type(16)));

#define NB 4
#define NS 2048
#define DM 256
#define NH 4
#define DHD 64
#define MR (NB*NS)      /* 8192 */
#define BHC (NB*NH)     /* 16 */
#define ACH 8
#define ACK (NS/ACH)    /* 256 keys per chunk */

__device__ __forceinline__ u16 f2b(float f){
    __hip_bfloat16 h = __float2bfloat16(f);
    return __builtin_bit_cast(u16, h);
}
__device__ __forceinline__ float b2f(u16 u){
    unsigned v = ((unsigned)u) << 16; float f; __builtin_memcpy(&f, &v, 4); return f;
}
__device__ __forceinline__ float fexp2(float x){
    float r; asm("v_exp_f32 %0, %1" : "=v"(r) : "v"(x)); return r;
}

#define MFMA16(a,b,c) __builtin_amdgcn_mfma_f32_16x16x32_bf16((a),(b),(c),0,0,0)
#define MFMA32(a,b,c) __builtin_amdgcn_mfma_f32_32x32x16_bf16((a),(b),(c),0,0,0)

// ---------------- casts ----------------
__global__ void k_cast_bf16(const float* __restrict__ src, u16* __restrict__ dst, int n){
    int i = (blockIdx.x*blockDim.x + threadIdx.x)*4;
    if (i + 3 < n){
        float4 v = *(const float4*)(src + i);
        dst[i+0] = f2b(v.x); dst[i+1] = f2b(v.y); dst[i+2] = f2b(v.z); dst[i+3] = f2b(v.w);
    }
}
__global__ void k_cast_w_t(const float* __restrict__ W, u16* __restrict__ Wt, int K, int Nc){
    int idx = blockIdx.x*blockDim.x + threadIdx.x;
    if (idx >= K*Nc) return;
    int k = idx % K, nc = idx / K;
    Wt[idx] = f2b(W[(size_t)k*Nc + nc]);
}
// cat left half: cat[row*512 + c] = Xb[row*256 + c], vectorized x8
__global__ void k_fill_x(const u16* __restrict__ Xb, u16* __restrict__ cat){
    int i = blockIdx.x*256 + threadIdx.x;          // MR*DM/8
    if (i >= MR*DM/8) return;
    int row = i >> 5, c8 = i & 31;
    *(u16x8*)(cat + (size_t)row*512 + c8*8) = *(const u16x8*)(Xb + (size_t)row*256 + c8*8);
}

// ---------------- shared GEMM core (verified) ----------------
#define GEMM_CORE(Aptr, Wptr, Kdim) \
    __shared__ __attribute__((aligned(16))) u16 As[64*72]; \
    __shared__ __attribute__((aligned(16))) u16 Bs[64*72]; \
    const int tid = threadIdx.x; \
    const int lane = tid & 63, widx = tid >> 6; \
    const int wr = widx >> 1, wc = widx & 1; \
    const int r16 = lane & 15, g = lane >> 4; \
    const int m0 = blockIdx.x * 64, n0 = blockIdx.y * 64; \
    f32x4 acc[2][2] = {}; \
    { const int nkt = (Kdim) >> 6; \
    for (int kt = 0; kt < nkt; ++kt){ \
        _Pragma("unroll") \
        for (int it = 0; it < 2; ++it){ \
            int ch = tid + it*256; \
            int row = ch >> 3, cc = ch & 7; \
            *(u16x8*)(As + row*72 + cc*8) = *(const u16x8*)((Aptr) + (size_t)(m0+row)*(Kdim) + kt*64 + cc*8); \
            *(u16x8*)(Bs + row*72 + cc*8) = *(const u16x8*)((Wptr) + (size_t)(n0+row)*(Kdim) + kt*64 + cc*8); \
        } \
        __syncthreads(); \
        _Pragma("unroll") \
        for (int s = 0; s < 2; ++s){ \
            bf16x8 a0 = *(const bf16x8*)(As + (wr*32 +      r16)*72 + s*32 + g*8); \
            bf16x8 a1 = *(const bf16x8*)(As + (wr*32 + 16 + r16)*72 + s*32 + g*8); \
            bf16x8 b0 = *(const bf16x8*)(Bs + (wc*32 +      r16)*72 + s*32 + g*8); \
            bf16x8 b1 = *(const bf16x8*)(Bs + (wc*32 + 16 + r16)*72 + s*32 + g*8); \
            acc[0][0] = MFMA16(a0, b0, acc[0][0]); \
            acc[0][1] = MFMA16(a0, b1, acc[0][1]); \
            acc[1][0] = MFMA16(a1, b0, acc[1][0]); \
            acc[1][1] = MFMA16(a1, b1, acc[1][1]); \
        } \
        __syncthreads(); \
    } }

// plain f32 out
__global__ __launch_bounds__(256) void k_gemm(const u16* __restrict__ A, const u16* __restrict__ Wt,
                                              const float* __restrict__ bias, float* __restrict__ C,
                                              int K, int Nc){
    GEMM_CORE(A, Wt, K)
#pragma unroll
    for (int mi = 0; mi < 2; ++mi)
#pragma unroll
    for (int ni = 0; ni < 2; ++ni){
        int row = m0 + wr*32 + mi*16 + g*4;
        int col = n0 + wc*32 + ni*16 + r16;
        float bc = bias[col];
        float* cp = C + (size_t)row*Nc + col;
#pragma unroll
        for (int rr = 0; rr < 4; ++rr) cp[(size_t)rr*Nc] = acc[mi][ni][rr] + bc;
    }
}
// bf16 out into cat right half (Nc=256)
__global__ __launch_bounds__(256) void k_gemm_cat(const u16* __restrict__ A, const u16* __restrict__ Wt,
                                                  const float* __restrict__ bias, u16* __restrict__ cat,
                                                  int K){
    GEMM_CORE(A, Wt, K)
#pragma unroll
    for (int mi = 0; mi < 2; ++mi)
#pragma unroll
    for (int ni = 0; ni < 2; ++ni){
        int row = m0 + wr*32 + mi*16 + g*4;
        int col = n0 + wc*32 + ni*16 + r16;
        float bc = bias[col];
        u16* cp = cat + (size_t)row*512 + 256 + col;
#pragma unroll
        for (int rr = 0; rr < 4; ++rr) cp[(size_t)rr*512] = f2b(acc[mi][ni][rr] + bc);
    }
}
// bf16 out head-split (b,h,n,dh), Nc=256
__global__ __launch_bounds__(256) void k_gemm_qk(const u16* __restrict__ A, const u16* __restrict__ Wt,
                                                 const float* __restrict__ bias, u16* __restrict__ Q,
                                                 int K){
    GEMM_CORE(A, Wt, K)
#pragma unroll
    for (int mi = 0; mi < 2; ++mi)
#pragma unroll
    for (int ni = 0; ni < 2; ++ni){
        int row = m0 + wr*32 + mi*16 + g*4;
        int col = n0 + wc*32 + ni*16 + r16;
        float bc = bias[col];
        int h = col >> 6, dh = col & 63;
#pragma unroll
        for (int rr = 0; rr < 4; ++rr){
            int r2 = row + rr;
            int b = r2 >> 11, n = r2 & (NS-1);
            Q[((size_t)(b*NH + h)*NS + n)*DHD + dh] = f2b(acc[mi][ni][rr] + bc);
        }
    }
}
// fused residual: Out = acc + bias + X ; optional bf16 copy
template<bool WRITEB>
__global__ __launch_bounds__(256) void k_gemm_resid(const u16* __restrict__ A, const u16* __restrict__ Wt,
                                                    const float* __restrict__ bias, const float* __restrict__ X,
                                                    float* __restrict__ OutF, u16* __restrict__ OutB,
                                                    int K, int Nc){
    GEMM_CORE(A, Wt, K)
#pragma unroll
    for (int mi = 0; mi < 2; ++mi)
#pragma unroll
    for (int ni = 0; ni < 2; ++ni){
        int row = m0 + wr*32 + mi*16 + g*4;
        int col = n0 + wc*32 + ni*16 + r16;
        float bc = bias[col];
#pragma unroll
        for (int rr = 0; rr < 4; ++rr){
            size_t idx = (size_t)(row+rr)*Nc + col;
            float v = acc[mi][ni][rr] + bc + X[idx];
            OutF[idx] = v;
            if (WRITEB) OutB[idx] = f2b(v);
        }
    }
}

// ---------------- qkv epilogue ----------------
__global__ void k_qkv_epi(const float* __restrict__ C, const float* __restrict__ kp,
                          u16* __restrict__ Q, u16* __restrict__ K, u16* __restrict__ VT){
    int idx = blockIdx.x*blockDim.x + threadIdx.x;
    if (idx >= BHC*NS*32) return;
    int dhp = idx & 31;
    int n   = (idx >> 5) & (NS-1);
    int bh  = idx >> 16;
    int b = bh >> 2, h = bh & 3;
    size_t crow = (size_t)(b*NS + n)*768 + h*192 + dhp*6;
    float q0 = C[crow+0], k0 = C[crow+1], v0 = C[crow+2];
    float q1 = C[crow+3], k1 = C[crow+4], v1 = C[crow+5];
    size_t kb = (size_t)b*(NS*DHD) + (size_t)n*DHD + dhp*2;
    float c0 = kp[kb], c1 = kp[kb+1];
    float s0 = kp[kb + (size_t)NB*NS*DHD], s1 = kp[kb + (size_t)NB*NS*DHD + 1];
    float qr0 = q0*c0 - q1*s0, qr1 = q1*c1 + q0*s1;
    float kr0 = k0*c0 - k1*s0, kr1 = k1*c1 + k0*s1;
    size_t qk = ((size_t)bh*NS + n)*DHD + dhp*2;
    Q[qk]   = f2b(qr0); Q[qk+1] = f2b(qr1);
    K[qk]   = f2b(kr0); K[qk+1] = f2b(kr1);
    size_t vt = ((size_t)bh*DHD + dhp*2)*NS + n;
    VT[vt]      = f2b(v0);
    VT[vt + NS] = f2b(v1);
}
__global__ void k_v_epi(const float* __restrict__ C, u16* __restrict__ VT){
    int idx = blockIdx.x*blockDim.x + threadIdx.x;
    if (idx >= BHC*NS*DHD) return;
    int n = idx & (NS-1); int dh = (idx >> 11) & 63; int bh = idx >> 17;
    int b = bh >> 2, h = bh & 3;
    VT[idx] = f2b(C[(size_t)(b*NS + n)*DM + h*DHD + dh]);
}

// ---------------- attention v4: swapped 32x32, log2-domain softmax, defer-max ----------------
__global__ __launch_bounds__(256) void k_attn3(const u16* __restrict__ Q, const u16* __restrict__ Kb,
                                               const u16* __restrict__ VT,
                                               u16* __restrict__ opart, float* __restrict__ mpart,
                                               float* __restrict__ lpart, float scale_l2e){
    const int tid = threadIdx.x, lane = tid & 63, widx = tid >> 6;
    const int l31 = lane & 31, hi = lane >> 5;
    const int gw = blockIdx.x*4 + widx;
    const int bh = gw >> 6, qt = gw & 63;
    const int q0 = qt * 32;
    const int ck = blockIdx.y;

    bf16x8 qf[4];
    {
        const u16* Qp = Q + ((size_t)bh*NS + q0 + l31)*DHD + hi*8;
#pragma unroll
        for (int kk = 0; kk < 4; ++kk){
            u16x8 raw = *(const u16x8*)(Qp + kk*16);
            u16x8 sc;
#pragma unroll
            for (int i = 0; i < 8; ++i) sc[i] = f2b(b2f(raw[i]) * scale_l2e);
            qf[kk] = __builtin_bit_cast(bf16x8, sc);
        }
    }

    f32x16 o0 = {}, o1 = {};
    float m_run = -1e30f, l_run = 0.f;
    const u16* Kbase = Kb + ((size_t)bh*NS + ck*ACK)*DHD;
    const u16* Vb0 = VT + ((size_t)bh*DHD +      l31)*NS + ck*ACK;
    const u16* Vb1 = VT + ((size_t)bh*DHD + 32 + l31)*NS + ck*ACK;

    for (int jt = 0; jt < ACK/32; ++jt){
        const u16* Kp = Kbase + (size_t)(jt*32 + l31)*DHD + hi*8;
        f32x16 s = {};
#pragma unroll
        for (int kk = 0; kk < 4; ++kk){
            bf16x8 kf = *(const bf16x8*)(Kp + kk*16);
            s = MFMA32(kf, qf[kk], s);
        }
        // tree max over 16 in-lane scores (log2 domain)
        float t[8];
#pragma unroll
        for (int i = 0; i < 8; ++i) t[i] = fmaxf(s[2*i], s[2*i+1]);
#pragma unroll
        for (int i = 0; i < 4; ++i) t[i] = fmaxf(t[i], t[i+4]);
        t[0] = fmaxf(t[0], t[2]); t[1] = fmaxf(t[1], t[3]);
        float mx = fmaxf(t[0], t[1]);
        mx = fmaxf(mx, __shfl_xor(mx, 32));
        // defer-max: rescale only when some lane's max grew past THR
        if (__any(mx > m_run + 8.0f)){
            float mn = fmaxf(m_run, mx);
            float corr = fexp2(m_run - mn);
            l_run *= corr;
            o0 *= corr; o1 *= corr;
            m_run = mn;
        }
        float p[16];
#pragma unroll
        for (int i = 0; i < 16; ++i) p[i] = fexp2(s[i] - m_run);
        float u[8];
#pragma unroll
        for (int i = 0; i < 8; ++i) u[i] = p[2*i] + p[2*i+1];
#pragma unroll
        for (int i = 0; i < 4; ++i) u[i] = u[i] + u[i+4];
        u[0] += u[2]; u[1] += u[3];
        float sum = u[0] + u[1];
        sum += __shfl_xor(sum, 32);
        l_run += sum;
        // pack P into B-frags
        unsigned c[8], x[8];
#pragma unroll
        for (int i = 0; i < 8; ++i)
            c[i] = ((unsigned)f2b(p[2*i+1]) << 16) | (unsigned)f2b(p[2*i]);
#pragma unroll
        for (int i = 0; i < 8; ++i) x[i] = __shfl_xor(c[i], 32);
        unsigned pb0w[4], pb1w[4];
        pb0w[0] = hi ? x[2] : c[0];  pb0w[1] = hi ? x[3] : c[1];
        pb0w[2] = hi ? c[2] : x[0];  pb0w[3] = hi ? c[3] : x[1];
        pb1w[0] = hi ? x[6] : c[4];  pb1w[1] = hi ? x[7] : c[5];
        pb1w[2] = hi ? c[6] : x[4];  pb1w[3] = hi ? c[7] : x[5];
        bf16x8 pb0, pb1;
        __builtin_memcpy(&pb0, pb0w, 16);
        __builtin_memcpy(&pb1, pb1w, 16);
        bf16x8 v00 = *(const bf16x8*)(Vb0 + jt*32 +      hi*8);
        bf16x8 v01 = *(const bf16x8*)(Vb0 + jt*32 + 16 + hi*8);
        bf16x8 v10 = *(const bf16x8*)(Vb1 + jt*32 +      hi*8);
        bf16x8 v11 = *(const bf16x8*)(Vb1 + jt*32 + 16 + hi*8);
        o0 = MFMA32(v00, pb0, o0);
        o0 = MFMA32(v01, pb1, o0);
        o1 = MFMA32(v10, pb0, o1);
        o1 = MFMA32(v11, pb1, o1);
    }
    const size_t rq = ((size_t)ck*BHC + bh)*NS + q0 + l31;
    if (!hi){ mpart[rq] = m_run; lpart[rq] = l_run; }
    u16* op = opart + rq*64;
#pragma unroll
    for (int r = 0; r < 16; ++r){
        int d = (r & 3) + 8*(r >> 2) + 4*hi;
        op[d]      = f2b(o0[r]);
        op[d + 32] = f2b(o1[r]);
    }
}

// combine ACH chunks -> ctx bf16 (b,n,256)   [log2 domain]
__global__ __launch_bounds__(256) void k_attn_comb(const u16* __restrict__ opart,
                                                   const float* __restrict__ mpart,
                                                   const float* __restrict__ lpart,
                                                   u16* __restrict__ ctx){
    int idx = blockIdx.x*256 + threadIdx.x;
    if (idx >= BHC*NS*64) return;
    int d = idx & 63; int n = (idx >> 6) & (NS-1); int bh = idx >> 17;
    size_t row = (size_t)bh*NS + n;
    const size_t CH = (size_t)BHC*NS;
    float M = -1e30f;
#pragma unroll
    for (int ck = 0; ck < ACH; ++ck) M = fmaxf(M, mpart[ck*CH + row]);
    float l = 0.f, o = 0.f;
#pragma unroll
    for (int ck = 0; ck < ACH; ++ck){
        float e = fexp2(mpart[ck*CH + row] - M);
        l += lpart[ck*CH + row] * e;
        o += b2f(opart[(ck*CH + row)*64 + d]) * e;
    }
    int b = bh >> 2, h = bh & 3;
    ctx[((size_t)b*NS + n)*DM + h*DHD + d] = f2b(o / l);
}

// ---------------- LN + GELU ----------------
__global__ __launch_bounds__(256) void k_ln_gelu(const float* __restrict__ C, const float* __restrict__ gam,
                                                 const float* __restrict__ bet, u16* __restrict__ hb){
    int row = blockIdx.x, t = threadIdx.x;
    const float* cr = C + (size_t)row*512;
    float x0 = cr[t], x1 = cr[t+256];
    float s = x0 + x1, q = x0*x0 + x1*x1;
#pragma unroll
    for (int offs = 1; offs < 64; offs <<= 1){
        s += __shfl_xor(s, offs);
        q += __shfl_xor(q, offs);
    }
    __shared__ float ss[4], qq[4];
    int w = t >> 6, ln = t & 63;
    if (ln == 0){ ss[w] = s; qq[w] = q; }
    __syncthreads();
    s = ss[0]+ss[1]+ss[2]+ss[3];
    q = qq[0]+qq[1]+qq[2]+qq[3];
    float mu = s * (1.f/512.f);
    float var = q * (1.f/512.f) - mu*mu;
    float rs = rsqrtf(var + 1e-5f);
    float y0 = (x0 - mu)*rs*gam[t]     + bet[t];
    float y1 = (x1 - mu)*rs*gam[t+256] + bet[t+256];
    float g0 = 0.5f*y0*(1.f + erff(y0*0.70710678118654752f));
    float g1 = 0.5f*y1*(1.f + erff(y1*0.70710678118654752f));
    hb[(size_t)row*512 + t]       = f2b(g0);
    hb[(size_t)row*512 + 256 + t] = f2b(g1);
}

// ---------------- host ----------------
extern "C" void kernel_launch(void* const* d_in, const int* in_sizes, int n_in,
                              void* d_out, int out_size, void* d_ws, size_t ws_size,
                              hipStream_t stream)
{
    const float* kp0   = (const float*)d_in[0];
    const float* kp1   = (const float*)d_in[1];
    const float* desc0 = (const float*)d_in[2];
    const float* desc1 = (const float*)d_in[3];
    const float* saWqkv= (const float*)d_in[4];
    const float* sabqkv= (const float*)d_in[5];
    const float* saWo  = (const float*)d_in[6];
    const float* sabo  = (const float*)d_in[7];
    const float* saW1  = (const float*)d_in[8];
    const float* sab1  = (const float*)d_in[9];
    const float* sag   = (const float*)d_in[10];
    const float* sabe  = (const float*)d_in[11];
    const float* saW2  = (const float*)d_in[12];
    const float* sab2  = (const float*)d_in[13];
    const float* caWqk = (const float*)d_in[14];
    const float* cabqk = (const float*)d_in[15];
    const float* caWv  = (const float*)d_in[16];
    const float* cabv  = (const float*)d_in[17];
    const float* caWo  = (const float*)d_in[18];
    const float* cabo  = (const float*)d_in[19];
    const float* caW1  = (const float*)d_in[20];
    const float* cab1  = (const float*)d_in[21];
    const float* cag   = (const float*)d_in[22];
    const float* cabe  = (const float*)d_in[23];
    const float* caW2  = (const float*)d_in[24];
    const float* cab2  = (const float*)d_in[25];

    char* ws = (char*)d_ws;
    size_t off = 0;
    auto alloc = [&](size_t b)->char*{ char* p = ws + off; off = (off + b + 255) & ~(size_t)255; return p; };

    u16* wqkvT = (u16*)alloc(768*256*2);
    u16* woST  = (u16*)alloc(256*256*2);
    u16* w1ST  = (u16*)alloc(512*512*2);
    u16* w2ST  = (u16*)alloc(256*512*2);
    u16* wqkT  = (u16*)alloc(256*256*2);
    u16* wvT   = (u16*)alloc(256*256*2);
    u16* woCT  = (u16*)alloc(256*256*2);
    u16* w1CT  = (u16*)alloc(512*512*2);
    u16* w2CT  = (u16*)alloc(256*512*2);
    u16* X0b   = (u16*)alloc((size_t)MR*DM*2);
    u16* X1b   = (u16*)alloc((size_t)MR*DM*2);
    u16* Qb    = (u16*)alloc((size_t)MR*DM*2);
    u16* Kbf   = (u16*)alloc((size_t)MR*DM*2);
    u16* VTa   = (u16*)alloc((size_t)MR*DM*2);
    u16* VT0   = (u16*)alloc((size_t)MR*DM*2);
    u16* ctxb  = (u16*)alloc((size_t)MR*DM*2);
    u16* midb0 = (u16*)alloc((size_t)MR*DM*2);
    u16* midb1 = (u16*)alloc((size_t)MR*DM*2);
    u16* catb  = (u16*)alloc((size_t)MR*512*2);
    u16* hb    = (u16*)alloc((size_t)MR*512*2);
    // union region: Cbuf (f32 8192x768 = 25.2 MB) and opart (bf16 ACH*16*2048*64 = 33.6 MB)
    char* uni  = alloc((size_t)ACH*BHC*NS*64*2);
    float* Cbuf = (float*)uni;
    u16*  opart = (u16*)uni;
    float* mid0= (float*)alloc((size_t)MR*DM*4);
    float* mid1= (float*)alloc((size_t)MR*DM*4);
    float* mpart = (float*)alloc((size_t)ACH*BHC*NS*4);
    float* lpart = (float*)alloc((size_t)ACH*BHC*NS*4);

    k_cast_w_t<<<768, 256, 0, stream>>>(saWqkv, wqkvT, 256, 768);
    k_cast_w_t<<<256, 256, 0, stream>>>(saWo,  woST, 256, 256);
    k_cast_w_t<<<1024,256, 0, stream>>>(saW1,  w1ST, 512, 512);
    k_cast_w_t<<<512, 256, 0, stream>>>(saW2,  w2ST, 512, 256);
    k_cast_w_t<<<256, 256, 0, stream>>>(caWqk, wqkT, 256, 256);
    k_cast_w_t<<<256, 256, 0, stream>>>(caWv,  wvT,  256, 256);
    k_cast_w_t<<<256, 256, 0, stream>>>(caWo,  woCT, 256, 256);
    k_cast_w_t<<<1024,256, 0, stream>>>(caW1,  w1CT, 512, 512);
    k_cast_w_t<<<512, 256, 0, stream>>>(caW2,  w2CT, 512, 256);
    k_cast_bf16<<<2048, 256, 0, stream>>>(desc0, X0b, MR*DM);
    k_cast_bf16<<<2048, 256, 0, stream>>>(desc1, X1b, MR*DM);

    const dim3 AG(256, ACH);
    const float SC = 0.125f * 1.44269504088896f;   // scale * log2(e)

    // ================= self block 0 =================
    k_gemm<<<dim3(128,12),256,0,stream>>>(X0b, wqkvT, sabqkv, Cbuf, 256, 768);
    k_qkv_epi<<<4096,256,0,stream>>>(Cbuf, kp0, Qb, Kbf, VTa);
    k_attn3<<<AG,256,0,stream>>>(Qb, Kbf, VTa, opart, mpart, lpart, SC);
    k_attn_comb<<<8192,256,0,stream>>>(opart, mpart, lpart, ctxb);
    k_fill_x<<<1024,256,0,stream>>>(X0b, catb);
    k_gemm_cat<<<dim3(128,4),256,0,stream>>>(ctxb, woST, sabo, catb, 256);
    k_gemm<<<dim3(128,8),256,0,stream>>>(catb, w1ST, sab1, Cbuf, 512, 512);
    k_ln_gelu<<<8192,256,0,stream>>>(Cbuf, sag, sabe, hb);
    k_gemm_resid<true><<<dim3(128,4),256,0,stream>>>(hb, w2ST, sab2, desc0, mid0, midb0, 512, 256);

    // ================= self block 1 =================
    k_gemm<<<dim3(128,12),256,0,stream>>>(X1b, wqkvT, sabqkv, Cbuf, 256, 768);
    k_qkv_epi<<<4096,256,0,stream>>>(Cbuf, kp1, Qb, Kbf, VTa);
    k_attn3<<<AG,256,0,stream>>>(Qb, Kbf, VTa, opart, mpart, lpart, SC);
    k_attn_comb<<<8192,256,0,stream>>>(opart, mpart, lpart, ctxb);
    k_fill_x<<<1024,256,0,stream>>>(X1b, catb);
    k_gemm_cat<<<dim3(128,4),256,0,stream>>>(ctxb, woST, sabo, catb, 256);
    k_gemm<<<dim3(128,8),256,0,stream>>>(catb, w1ST, sab1, Cbuf, 512, 512);
    k_ln_gelu<<<8192,256,0,stream>>>(Cbuf, sag, sabe, hb);
    k_gemm_resid<true><<<dim3(128,4),256,0,stream>>>(hb, w2ST, sab2, desc1, mid1, midb1, 512, 256);

    // ================= cross projections =================
    k_gemm_qk<<<dim3(128,4),256,0,stream>>>(midb0, wqkT, cabqk, Qb, 256);    // qk0
    k_gemm_qk<<<dim3(128,4),256,0,stream>>>(midb1, wqkT, cabqk, Kbf, 256);   // qk1
    k_gemm<<<dim3(128,4),256,0,stream>>>(midb1, wvT, cabv, Cbuf, 256, 256);
    k_v_epi<<<8192,256,0,stream>>>(Cbuf, VTa);                               // v1^T
    k_gemm<<<dim3(128,4),256,0,stream>>>(midb0, wvT, cabv, Cbuf, 256, 256);
    k_v_epi<<<8192,256,0,stream>>>(Cbuf, VT0);                               // v0^T

    float* out0 = (float*)d_out;
    float* out1 = out0 + (size_t)MR*DM;

    // ---- cross side 0 ----
    k_attn3<<<AG,256,0,stream>>>(Qb, Kbf, VTa, opart, mpart, lpart, SC);
    k_attn_comb<<<8192,256,0,stream>>>(opart, mpart, lpart, ctxb);
    k_fill_x<<<1024,256,0,stream>>>(midb0, catb);
    k_gemm_cat<<<dim3(128,4),256,0,stream>>>(ctxb, woCT, cabo, catb, 256);
    k_gemm<<<dim3(128,8),256,0,stream>>>(catb, w1CT, cab1, Cbuf, 512, 512);
    k_ln_gelu<<<8192,256,0,stream>>>(Cbuf, cag, cabe, hb);
    k_gemm_resid<false><<<dim3(128,4),256,0,stream>>>(hb, w2CT, cab2, mid0, out0, nullptr, 512, 256);

    // ---- cross side 1 ----
    k_attn3<<<AG,256,0,stream>>>(Kbf, Qb, VT0, opart, mpart, lpart, SC);
    k_attn_comb<<<8192,256,0,stream>>>(opart, mpart, lpart, ctxb);
    k_fill_x<<<1024,256,0,stream>>>(midb1, catb);
    k_gemm_cat<<<dim3(128,4),256,0,stream>>>(ctxb, woCT, cabo, catb, 256);
    k_gemm<<<dim3(128,8),256,0,stream>>>(catb, w1CT, cab1, Cbuf, 512, 512);
    k_ln_gelu<<<8192,256,0,stream>>>(Cbuf, cag, cabe, hb);
    k_gemm_resid<false><<<dim3(128,4),256,0,stream>>>(hb, w2CT, cab2, mid1, out1, nullptr, 512, 256);

    (void)in_sizes; (void)n_in; (void)out_size; (void)ws_size;
}

// Round 23
// 505.390 us; speedup vs baseline: 1.7301x; 1.2304x over previous
//
#include <hip/hip_runtime.h>
#include <hip/hip_bf16.h>

typedef unsigned short u16;
typedef short bf16x8 __attribute__((ext_vector_type(8)));
typedef unsigned short u16x8 __attribute__((ext_vector_type(8)));
typedef float f32x4 __attribute__((ext_vector_type(4)));
typedef float f32x16 __attribute__((ext_vector_type(16)));

#define NB 4
#define NS 2048
#define DM 256
#define NH 4
#define DHD 64
#define MR (NB*NS)      /* 8192 */
#define BHC (NB*NH)     /* 16 */
#define BH2 32          /* two sides batched */
#define M2 (2*MR)       /* 16384 */
#define ACH 4
#define ACK (NS/ACH)    /* 512 keys per chunk */
#define HS ((size_t)BHC*NS*DHD)   /* half stride in Q2/K2/V2 */

__device__ __forceinline__ u16 f2b(float f){
    __hip_bfloat16 h = __float2bfloat16(f);
    return __builtin_bit_cast(u16, h);
}
__device__ __forceinline__ float b2f(u16 u){
    unsigned v = ((unsigned)u) << 16; float f; __builtin_memcpy(&f, &v, 4); return f;
}
__device__ __forceinline__ float fexp2(float x){
    float r; asm("v_exp_f32 %0, %1" : "=v"(r) : "v"(x)); return r;
}

#define MFMA16(a,b,c) __builtin_amdgcn_mfma_f32_16x16x32_bf16((a),(b),(c),0,0,0)
#define MFMA32(a,b,c) __builtin_amdgcn_mfma_f32_32x32x16_bf16((a),(b),(c),0,0,0)

// ---------------- casts ----------------
// both descs -> X01b (vectorized x4)
__global__ void k_cast_desc(const float* __restrict__ d0, const float* __restrict__ d1, u16* __restrict__ dst){
    int i = (blockIdx.x*256 + threadIdx.x)*4;          // over 2*MR*DM
    if (i + 3 >= 2*MR*DM) return;
    const float* src = (i < MR*DM) ? d0 : d1;
    int j = (i < MR*DM) ? i : i - MR*DM;
    float4 v = *(const float4*)(src + j);
    dst[i+0] = f2b(v.x); dst[i+1] = f2b(v.y); dst[i+2] = f2b(v.z); dst[i+3] = f2b(v.w);
}
__device__ __forceinline__ void wt_one(const float* W, u16* Wt, int idx, int K, int Nc){
    int k = idx % K, nc = idx / K;
    Wt[idx] = f2b(W[(size_t)k*Nc + nc]);
}
__global__ void k_cwt1(const float* __restrict__ W, u16* __restrict__ Wt, int K, int Nc){
    int idx = blockIdx.x*256 + threadIdx.x;
    if (idx < K*Nc) wt_one(W, Wt, idx, K, Nc);
}
__global__ void k_cwt4(const float* W0, const float* W1, const float* W2, const float* W3,
                       u16* T0, u16* T1, u16* T2, u16* T3){
    int idx = blockIdx.x*256 + threadIdx.x;            // 4 x 65536
    int w = idx >> 16, j = idx & 65535;
    const float* W = (w==0)?W0:(w==1)?W1:(w==2)?W2:W3;
    u16* T = (w==0)?T0:(w==1)?T1:(w==2)?T2:T3;
    wt_one(W, T, j, 256, 256);
}
__global__ void k_cwt2a(const float* W0, const float* W1, u16* T0, u16* T1){
    int idx = blockIdx.x*256 + threadIdx.x;            // 2 x 262144
    int w = idx >> 18, j = idx & 262143;
    wt_one(w? W1:W0, w? T1:T0, j, 512, 512);
}
__global__ void k_cwt2b(const float* W0, const float* W1, u16* T0, u16* T1){
    int idx = blockIdx.x*256 + threadIdx.x;            // 2 x 131072
    int w = idx >> 17, j = idx & 131071;
    wt_one(w? W1:W0, w? T1:T0, j, 512, 256);
}
// cat left half
__global__ void k_fill_x(const u16* __restrict__ Xb, u16* __restrict__ cat){
    int i = blockIdx.x*256 + threadIdx.x;              // M2*DM/8
    if (i >= M2*DM/8) return;
    int row = i >> 5, c8 = i & 31;
    *(u16x8*)(cat + (size_t)row*512 + c8*8) = *(const u16x8*)(Xb + (size_t)row*256 + c8*8);
}

// ---------------- shared GEMM core (verified) ----------------
#define GEMM_CORE(Aptr, Wptr, Kdim) \
    __shared__ __attribute__((aligned(16))) u16 As[64*72]; \
    __shared__ __attribute__((aligned(16))) u16 Bs[64*72]; \
    const int tid = threadIdx.x; \
    const int lane = tid & 63, widx = tid >> 6; \
    const int wr = widx >> 1, wc = widx & 1; \
    const int r16 = lane & 15, g = lane >> 4; \
    const int m0 = blockIdx.x * 64, n0 = blockIdx.y * 64; \
    f32x4 acc[2][2] = {}; \
    { const int nkt = (Kdim) >> 6; \
    for (int kt = 0; kt < nkt; ++kt){ \
        _Pragma("unroll") \
        for (int it = 0; it < 2; ++it){ \
            int ch = tid + it*256; \
            int row = ch >> 3, cc = ch & 7; \
            *(u16x8*)(As + row*72 + cc*8) = *(const u16x8*)((Aptr) + (size_t)(m0+row)*(Kdim) + kt*64 + cc*8); \
            *(u16x8*)(Bs + row*72 + cc*8) = *(const u16x8*)((Wptr) + (size_t)(n0+row)*(Kdim) + kt*64 + cc*8); \
        } \
        __syncthreads(); \
        _Pragma("unroll") \
        for (int s = 0; s < 2; ++s){ \
            bf16x8 a0 = *(const bf16x8*)(As + (wr*32 +      r16)*72 + s*32 + g*8); \
            bf16x8 a1 = *(const bf16x8*)(As + (wr*32 + 16 + r16)*72 + s*32 + g*8); \
            bf16x8 b0 = *(const bf16x8*)(Bs + (wc*32 +      r16)*72 + s*32 + g*8); \
            bf16x8 b1 = *(const bf16x8*)(Bs + (wc*32 + 16 + r16)*72 + s*32 + g*8); \
            acc[0][0] = MFMA16(a0, b0, acc[0][0]); \
            acc[0][1] = MFMA16(a0, b1, acc[0][1]); \
            acc[1][0] = MFMA16(a1, b0, acc[1][0]); \
            acc[1][1] = MFMA16(a1, b1, acc[1][1]); \
        } \
        __syncthreads(); \
    } }

// plain f32 out
__global__ __launch_bounds__(256) void k_gemm(const u16* __restrict__ A, const u16* __restrict__ Wt,
                                              const float* __restrict__ bias, float* __restrict__ C,
                                              int K, int Nc){
    GEMM_CORE(A, Wt, K)
#pragma unroll
    for (int mi = 0; mi < 2; ++mi)
#pragma unroll
    for (int ni = 0; ni < 2; ++ni){
        int row = m0 + wr*32 + mi*16 + g*4;
        int col = n0 + wc*32 + ni*16 + r16;
        float bc = bias[col];
        float* cp = C + (size_t)row*Nc + col;
#pragma unroll
        for (int rr = 0; rr < 4; ++rr) cp[(size_t)rr*Nc] = acc[mi][ni][rr] + bc;
    }
}
// bf16 out into cat right half (Nc=256)
__global__ __launch_bounds__(256) void k_gemm_cat(const u16* __restrict__ A, const u16* __restrict__ Wt,
                                                  const float* __restrict__ bias, u16* __restrict__ cat,
                                                  int K){
    GEMM_CORE(A, Wt, K)
#pragma unroll
    for (int mi = 0; mi < 2; ++mi)
#pragma unroll
    for (int ni = 0; ni < 2; ++ni){
        int row = m0 + wr*32 + mi*16 + g*4;
        int col = n0 + wc*32 + ni*16 + r16;
        float bc = bias[col];
        u16* cp = cat + (size_t)row*512 + 256 + col;
#pragma unroll
        for (int rr = 0; rr < 4; ++rr) cp[(size_t)rr*512] = f2b(acc[mi][ni][rr] + bc);
    }
}
// dual head-split bf16 out (Q-role and K-role), Nc=256, M=8192 per call
__global__ __launch_bounds__(256) void k_gemm_qk(const u16* __restrict__ A, const u16* __restrict__ Wt,
                                                 const float* __restrict__ bias,
                                                 u16* __restrict__ dstQ, u16* __restrict__ dstK, int K){
    GEMM_CORE(A, Wt, K)
#pragma unroll
    for (int mi = 0; mi < 2; ++mi)
#pragma unroll
    for (int ni = 0; ni < 2; ++ni){
        int row = m0 + wr*32 + mi*16 + g*4;
        int col = n0 + wc*32 + ni*16 + r16;
        float bc = bias[col];
        int h = col >> 6, dh = col & 63;
#pragma unroll
        for (int rr = 0; rr < 4; ++rr){
            int r2 = row + rr;
            int b = r2 >> 11, n = r2 & (NS-1);
            u16 v = f2b(acc[mi][ni][rr] + bc);
            size_t off = ((size_t)(b*NH + h)*NS + n)*DHD + dh;
            dstQ[off] = v;
            dstK[off] = v;
        }
    }
}
// V^T direct out: VT[(bh*64+dh)*NS + n], M=8192 per call
__global__ __launch_bounds__(256) void k_gemm_vt(const u16* __restrict__ A, const u16* __restrict__ Wt,
                                                 const float* __restrict__ bias, u16* __restrict__ VT, int K){
    GEMM_CORE(A, Wt, K)
#pragma unroll
    for (int mi = 0; mi < 2; ++mi)
#pragma unroll
    for (int ni = 0; ni < 2; ++ni){
        int row = m0 + wr*32 + mi*16 + g*4;
        int col = n0 + wc*32 + ni*16 + r16;
        float bc = bias[col];
        int h = col >> 6, dh = col & 63;
#pragma unroll
        for (int rr = 0; rr < 4; ++rr){
            int r2 = row + rr;
            int b = r2 >> 11, n = r2 & (NS-1);
            VT[((size_t)(b*NH + h)*DHD + dh)*NS + n] = f2b(acc[mi][ni][rr] + bc);
        }
    }
}
// self resid: out = acc + bias + desc(f32), bf16 out only; M=16384 (row<MR -> X0 else X1)
__global__ __launch_bounds__(256) void k_gemm_resid_mid(const u16* __restrict__ A, const u16* __restrict__ Wt,
                                                        const float* __restrict__ bias,
                                                        const float* __restrict__ X0, const float* __restrict__ X1,
                                                        u16* __restrict__ OutB, int K){
    GEMM_CORE(A, Wt, K)
#pragma unroll
    for (int mi = 0; mi < 2; ++mi)
#pragma unroll
    for (int ni = 0; ni < 2; ++ni){
        int row = m0 + wr*32 + mi*16 + g*4;
        int col = n0 + wc*32 + ni*16 + r16;
        float bc = bias[col];
#pragma unroll
        for (int rr = 0; rr < 4; ++rr){
            int r2 = row + rr;
            const float* X = (r2 < MR) ? X0 : X1;
            size_t xi = (size_t)(r2 < MR ? r2 : r2 - MR)*DM + col;
            OutB[(size_t)r2*DM + col] = f2b(acc[mi][ni][rr] + bc + X[xi]);
        }
    }
}
// final resid: out f32 = acc + bias + b2f(Xb); M=16384, writes d_out directly
__global__ __launch_bounds__(256) void k_gemm_resid_out(const u16* __restrict__ A, const u16* __restrict__ Wt,
                                                        const float* __restrict__ bias,
                                                        const u16* __restrict__ Xb, float* __restrict__ OutF, int K){
    GEMM_CORE(A, Wt, K)
#pragma unroll
    for (int mi = 0; mi < 2; ++mi)
#pragma unroll
    for (int ni = 0; ni < 2; ++ni){
        int row = m0 + wr*32 + mi*16 + g*4;
        int col = n0 + wc*32 + ni*16 + r16;
        float bc = bias[col];
#pragma unroll
        for (int rr = 0; rr < 4; ++rr){
            size_t idx = (size_t)(row+rr)*DM + col;
            OutF[idx] = acc[mi][ni][rr] + bc + b2f(Xb[idx]);
        }
    }
}

// ---------------- qkv epilogue (per side; dst offset by side*HS) ----------------
__global__ void k_qkv_epi(const float* __restrict__ C, const float* __restrict__ kp,
                          u16* __restrict__ Q, u16* __restrict__ K, u16* __restrict__ VT){
    int idx = blockIdx.x*blockDim.x + threadIdx.x;
    if (idx >= BHC*NS*32) return;
    int dhp = idx & 31;
    int n   = (idx >> 5) & (NS-1);
    int bh  = idx >> 16;
    int b = bh >> 2, h = bh & 3;
    size_t crow = (size_t)(b*NS + n)*768 + h*192 + dhp*6;
    float q0 = C[crow+0], k0 = C[crow+1], v0 = C[crow+2];
    float q1 = C[crow+3], k1 = C[crow+4], v1 = C[crow+5];
    size_t kb = (size_t)b*(NS*DHD) + (size_t)n*DHD + dhp*2;
    float c0 = kp[kb], c1 = kp[kb+1];
    float s0 = kp[kb + (size_t)NB*NS*DHD], s1 = kp[kb + (size_t)NB*NS*DHD + 1];
    float qr0 = q0*c0 - q1*s0, qr1 = q1*c1 + q0*s1;
    float kr0 = k0*c0 - k1*s0, kr1 = k1*c1 + k0*s1;
    size_t qk = ((size_t)bh*NS + n)*DHD + dhp*2;
    Q[qk]   = f2b(qr0); Q[qk+1] = f2b(qr1);
    K[qk]   = f2b(kr0); K[qk+1] = f2b(kr1);
    size_t vt = ((size_t)bh*DHD + dhp*2)*NS + n;
    VT[vt]      = f2b(v0);
    VT[vt + NS] = f2b(v1);
}

// ---------------- attention (swapped 32x32, log2 softmax, defer-max); 32 bh ----------------
__global__ __launch_bounds__(256) void k_attn3(const u16* __restrict__ Q, const u16* __restrict__ Kb,
                                               const u16* __restrict__ VT,
                                               u16* __restrict__ opart, float* __restrict__ mpart,
                                               float* __restrict__ lpart, float scale_l2e){
    const int tid = threadIdx.x, lane = tid & 63, widx = tid >> 6;
    const int l31 = lane & 31, hi = lane >> 5;
    const int gw = blockIdx.x*4 + widx;          // 0..2047
    const int bh = gw >> 6, qt = gw & 63;        // bh 0..31
    const int q0 = qt * 32;
    const int ck = blockIdx.y;

    bf16x8 qf[4];
    {
        const u16* Qp = Q + ((size_t)bh*NS + q0 + l31)*DHD + hi*8;
#pragma unroll
        for (int kk = 0; kk < 4; ++kk){
            u16x8 raw = *(const u16x8*)(Qp + kk*16);
            u16x8 sc;
#pragma unroll
            for (int i = 0; i < 8; ++i) sc[i] = f2b(b2f(raw[i]) * scale_l2e);
            qf[kk] = __builtin_bit_cast(bf16x8, sc);
        }
    }

    f32x16 o0 = {}, o1 = {};
    float m_run = -1e30f, l_run = 0.f;
    const u16* Kbase = Kb + ((size_t)bh*NS + ck*ACK)*DHD;
    const u16* Vb0 = VT + ((size_t)bh*DHD +      l31)*NS + ck*ACK;
    const u16* Vb1 = VT + ((size_t)bh*DHD + 32 + l31)*NS + ck*ACK;

    for (int jt = 0; jt < ACK/32; ++jt){
        const u16* Kp = Kbase + (size_t)(jt*32 + l31)*DHD + hi*8;
        f32x16 s = {};
#pragma unroll
        for (int kk = 0; kk < 4; ++kk){
            bf16x8 kf = *(const bf16x8*)(Kp + kk*16);
            s = MFMA32(kf, qf[kk], s);
        }
        float t[8];
#pragma unroll
        for (int i = 0; i < 8; ++i) t[i] = fmaxf(s[2*i], s[2*i+1]);
#pragma unroll
        for (int i = 0; i < 4; ++i) t[i] = fmaxf(t[i], t[i+4]);
        t[0] = fmaxf(t[0], t[2]); t[1] = fmaxf(t[1], t[3]);
        float mx = fmaxf(t[0], t[1]);
        mx = fmaxf(mx, __shfl_xor(mx, 32));
        if (__any(mx > m_run + 8.0f)){
            float mn = fmaxf(m_run, mx);
            float corr = fexp2(m_run - mn);
            l_run *= corr;
            o0 *= corr; o1 *= corr;
            m_run = mn;
        }
        float p[16];
#pragma unroll
        for (int i = 0; i < 16; ++i) p[i] = fexp2(s[i] - m_run);
        float u[8];
#pragma unroll
        for (int i = 0; i < 8; ++i) u[i] = p[2*i] + p[2*i+1];
#pragma unroll
        for (int i = 0; i < 4; ++i) u[i] = u[i] + u[i+4];
        u[0] += u[2]; u[1] += u[3];
        float sum = u[0] + u[1];
        sum += __shfl_xor(sum, 32);
        l_run += sum;
        unsigned c[8], x[8];
#pragma unroll
        for (int i = 0; i < 8; ++i)
            c[i] = ((unsigned)f2b(p[2*i+1]) << 16) | (unsigned)f2b(p[2*i]);
#pragma unroll
        for (int i = 0; i < 8; ++i) x[i] = __shfl_xor(c[i], 32);
        unsigned pb0w[4], pb1w[4];
        pb0w[0] = hi ? x[2] : c[0];  pb0w[1] = hi ? x[3] : c[1];
        pb0w[2] = hi ? c[2] : x[0];  pb0w[3] = hi ? c[3] : x[1];
        pb1w[0] = hi ? x[6] : c[4];  pb1w[1] = hi ? x[7] : c[5];
        pb1w[2] = hi ? c[6] : x[4];  pb1w[3] = hi ? c[7] : x[5];
        bf16x8 pb0, pb1;
        __builtin_memcpy(&pb0, pb0w, 16);
        __builtin_memcpy(&pb1, pb1w, 16);
        bf16x8 v00 = *(const bf16x8*)(Vb0 + jt*32 +      hi*8);
        bf16x8 v01 = *(const bf16x8*)(Vb0 + jt*32 + 16 + hi*8);
        bf16x8 v10 = *(const bf16x8*)(Vb1 + jt*32 +      hi*8);
        bf16x8 v11 = *(const bf16x8*)(Vb1 + jt*32 + 16 + hi*8);
        o0 = MFMA32(v00, pb0, o0);
        o0 = MFMA32(v01, pb1, o0);
        o1 = MFMA32(v10, pb0, o1);
        o1 = MFMA32(v11, pb1, o1);
    }
    const size_t rq = ((size_t)ck*BH2 + bh)*NS + q0 + l31;
    if (!hi){ mpart[rq] = m_run; lpart[rq] = l_run; }
    u16* op = opart + rq*64;
#pragma unroll
    for (int r = 0; r < 16; ++r){
        int d = (r & 3) + 8*(r >> 2) + 4*hi;
        op[d]      = f2b(o0[r]);
        op[d + 32] = f2b(o1[r]);
    }
}

// combine ACH chunks -> ctx2 bf16 ([side](b,n,256))
__global__ __launch_bounds__(256) void k_attn_comb(const u16* __restrict__ opart,
                                                   const float* __restrict__ mpart,
                                                   const float* __restrict__ lpart,
                                                   u16* __restrict__ ctx){
    int idx = blockIdx.x*256 + threadIdx.x;            // BH2*NS*64
    if (idx >= BH2*NS*64) return;
    int d = idx & 63; int n = (idx >> 6) & (NS-1); int bh2 = idx >> 17;
    size_t row = (size_t)bh2*NS + n;
    const size_t CH = (size_t)BH2*NS;
    float M = -1e30f;
#pragma unroll
    for (int ck = 0; ck < ACH; ++ck) M = fmaxf(M, mpart[ck*CH + row]);
    float l = 0.f, o = 0.f;
#pragma unroll
    for (int ck = 0; ck < ACH; ++ck){
        float e = fexp2(mpart[ck*CH + row] - M);
        l += lpart[ck*CH + row] * e;
        o += b2f(opart[(ck*CH + row)*64 + d]) * e;
    }
    int side = bh2 >> 4, bh = bh2 & 15;
    int b = bh >> 2, h = bh & 3;
    ctx[((size_t)side*MR + (size_t)b*NS + n)*DM + h*DHD + d] = f2b(o / l);
}

// ---------------- LN + GELU ----------------
__global__ __launch_bounds__(256) void k_ln_gelu(const float* __restrict__ C, const float* __restrict__ gam,
                                                 const float* __restrict__ bet, u16* __restrict__ hb){
    int row = blockIdx.x, t = threadIdx.x;
    const float* cr = C + (size_t)row*512;
    float x0 = cr[t], x1 = cr[t+256];
    float s = x0 + x1, q = x0*x0 + x1*x1;
#pragma unroll
    for (int offs = 1; offs < 64; offs <<= 1){
        s += __shfl_xor(s, offs);
        q += __shfl_xor(q, offs);
    }
    __shared__ float ss[4], qq[4];
    int w = t >> 6, ln = t & 63;
    if (ln == 0){ ss[w] = s; qq[w] = q; }
    __syncthreads();
    s = ss[0]+ss[1]+ss[2]+ss[3];
    q = qq[0]+qq[1]+qq[2]+qq[3];
    float mu = s * (1.f/512.f);
    float var = q * (1.f/512.f) - mu*mu;
    float rs = rsqrtf(var + 1e-5f);
    float y0 = (x0 - mu)*rs*gam[t]     + bet[t];
    float y1 = (x1 - mu)*rs*gam[t+256] + bet[t+256];
    float g0 = 0.5f*y0*(1.f + erff(y0*0.70710678118654752f));
    float g1 = 0.5f*y1*(1.f + erff(y1*0.70710678118654752f));
    hb[(size_t)row*512 + t]       = f2b(g0);
    hb[(size_t)row*512 + 256 + t] = f2b(g1);
}

// ---------------- host ----------------
extern "C" void kernel_launch(void* const* d_in, const int* in_sizes, int n_in,
                              void* d_out, int out_size, void* d_ws, size_t ws_size,
                              hipStream_t stream)
{
    const float* kp0   = (const float*)d_in[0];
    const float* kp1   = (const float*)d_in[1];
    const float* desc0 = (const float*)d_in[2];
    const float* desc1 = (const float*)d_in[3];
    const float* saWqkv= (const float*)d_in[4];
    const float* sabqkv= (const float*)d_in[5];
    const float* saWo  = (const float*)d_in[6];
    const float* sabo  = (const float*)d_in[7];
    const float* saW1  = (const float*)d_in[8];
    const float* sab1  = (const float*)d_in[9];
    const float* sag   = (const float*)d_in[10];
    const float* sabe  = (const float*)d_in[11];
    const float* saW2  = (const float*)d_in[12];
    const float* sab2  = (const float*)d_in[13];
    const float* caWqk = (const float*)d_in[14];
    const float* cabqk = (const float*)d_in[15];
    const float* caWv  = (const float*)d_in[16];
    const float* cabv  = (const float*)d_in[17];
    const float* caWo  = (const float*)d_in[18];
    const float* cabo  = (const float*)d_in[19];
    const float* caW1  = (const float*)d_in[20];
    const float* cab1  = (const float*)d_in[21];
    const float* cag   = (const float*)d_in[22];
    const float* cabe  = (const float*)d_in[23];
    const float* caW2  = (const float*)d_in[24];
    const float* cab2  = (const float*)d_in[25];

    char* ws = (char*)d_ws;
    size_t off = 0;
    auto alloc = [&](size_t b)->char*{ char* p = ws + off; off = (off + b + 255) & ~(size_t)255; return p; };

    u16* wqkvT = (u16*)alloc(768*256*2);
    u16* woST  = (u16*)alloc(256*256*2);
    u16* w1ST  = (u16*)alloc(512*512*2);
    u16* w2ST  = (u16*)alloc(256*512*2);
    u16* wqkT  = (u16*)alloc(256*256*2);
    u16* wvT   = (u16*)alloc(256*256*2);
    u16* woCT  = (u16*)alloc(256*256*2);
    u16* w1CT  = (u16*)alloc(512*512*2);
    u16* w2CT  = (u16*)alloc(256*512*2);
    u16* X01b  = (u16*)alloc((size_t)M2*DM*2);
    u16* Q2    = (u16*)alloc((size_t)BH2*NS*DHD*2);
    u16* K2    = (u16*)alloc((size_t)BH2*NS*DHD*2);
    u16* V2    = (u16*)alloc((size_t)BH2*NS*DHD*2);
    u16* ctx2  = (u16*)alloc((size_t)M2*DM*2);
    u16* midb2 = (u16*)alloc((size_t)M2*DM*2);
    u16* cat2  = (u16*)alloc((size_t)M2*512*2);        // hb2 aliases cat2 (cat dead after W1)
    u16* hb2   = cat2;
    char* uni  = alloc(33554432);                      // Cbuf(qkv 25MB / FFN 33.5MB) U opart(33.5MB)
    float* Cbuf = (float*)uni;
    u16*  opart = (u16*)uni;
    float* mpart = (float*)alloc((size_t)ACH*BH2*NS*4);
    float* lpart = (float*)alloc((size_t)ACH*BH2*NS*4);

    // ---- casts ----
    k_cwt1 <<<768, 256, 0, stream>>>(saWqkv, wqkvT, 256, 768);
    k_cwt4 <<<1024,256, 0, stream>>>(saWo, caWqk, caWv, caWo, woST, wqkT, wvT, woCT);
    k_cwt2a<<<2048,256, 0, stream>>>(saW1, caW1, w1ST, w1CT);
    k_cwt2b<<<1024,256, 0, stream>>>(saW2, caW2, w2ST, w2CT);
    k_cast_desc<<<4096,256,0,stream>>>(desc0, desc1, X01b);

    const dim3 AG(512, ACH);
    const float SC = 0.125f * 1.44269504088896f;

    // ================= self blocks (batched) =================
    k_gemm<<<dim3(128,12),256,0,stream>>>(X01b,            wqkvT, sabqkv, Cbuf, 256, 768);
    k_qkv_epi<<<4096,256,0,stream>>>(Cbuf, kp0, Q2, K2, V2);
    k_gemm<<<dim3(128,12),256,0,stream>>>(X01b + (size_t)MR*DM, wqkvT, sabqkv, Cbuf, 256, 768);
    k_qkv_epi<<<4096,256,0,stream>>>(Cbuf, kp1, Q2 + HS, K2 + HS, V2 + HS);
    k_attn3<<<AG,256,0,stream>>>(Q2, K2, V2, opart, mpart, lpart, SC);
    k_attn_comb<<<16384,256,0,stream>>>(opart, mpart, lpart, ctx2);
    k_fill_x<<<2048,256,0,stream>>>(X01b, cat2);
    k_gemm_cat<<<dim3(256,4),256,0,stream>>>(ctx2, woST, sabo, cat2, 256);
    k_gemm<<<dim3(256,8),256,0,stream>>>(cat2, w1ST, sab1, Cbuf, 512, 512);
    k_ln_gelu<<<16384,256,0,stream>>>(Cbuf, sag, sabe, hb2);
    k_gemm_resid_mid<<<dim3(256,4),256,0,stream>>>(hb2, w2ST, sab2, desc0, desc1, midb2, 512);

    // ================= cross projections =================
    // Q2 = [qk0 | qk1], K2 = [qk1 | qk0], V2 = [v1 | v0]
    k_gemm_qk<<<dim3(128,4),256,0,stream>>>(midb2,                wqkT, cabqk, Q2,      K2 + HS, 256); // qk0
    k_gemm_qk<<<dim3(128,4),256,0,stream>>>(midb2 + (size_t)MR*DM, wqkT, cabqk, Q2 + HS, K2,      256); // qk1
    k_gemm_vt<<<dim3(128,4),256,0,stream>>>(midb2 + (size_t)MR*DM, wvT,  cabv,  V2,      256);          // v1 -> side0
    k_gemm_vt<<<dim3(128,4),256,0,stream>>>(midb2,                wvT,  cabv,  V2 + HS, 256);           // v0 -> side1

    // ================= cross blocks (batched) =================
    k_attn3<<<AG,256,0,stream>>>(Q2, K2, V2, opart, mpart, lpart, SC);
    k_attn_comb<<<16384,256,0,stream>>>(opart, mpart, lpart, ctx2);
    k_fill_x<<<2048,256,0,stream>>>(midb2, cat2);
    k_gemm_cat<<<dim3(256,4),256,0,stream>>>(ctx2, woCT, cabo, cat2, 256);
    k_gemm<<<dim3(256,8),256,0,stream>>>(cat2, w1CT, cab1, Cbuf, 512, 512);
    k_ln_gelu<<<16384,256,0,stream>>>(Cbuf, cag, cabe, hb2);
    k_gemm_resid_out<<<dim3(256,4),256,0,stream>>>(hb2, w2CT, cab2, midb2, (float*)d_out, 512);

    (void)in_sizes; (void)n_in; (void)out_size; (void)ws_size;
}